// Round 10
// baseline (315.141 us; speedup 1.0000x reference)
//
#include <hip/hip_runtime.h>
#include <math.h>

#define E 1024
#define NH 16
#define HD 64
#define BSZ_ 4
#define SEQ_ 1500
#define M_ (BSZ_ * SEQ_)                 // 6000
#define SZE ((size_t)M_ * (size_t)E)     // 6,144,000
#define QSC (0.125f * 1.44269504f)       // fold log2e: P = exp2(s)

// ws layout (ushort offsets), tier-2 fast path:
#define QA_OFF  0u                        // Q / attn-out bf16 [6000][1024]
#define XB_OFF  6144000u                  // X bf16 [6000][1024]
#define WB_OFF  12288000u                 // [Wk;Wv;Wq*QSC] bf16 [3072][1024]
#define WOB_OFF 15433728u                 // Wo bf16 [1024][1024]
#define WS_NEED_BYTES ((size_t)(16482304u) * 2u)          // 32,964,608
// tier-3 adds: P0|P1 fp32 [2][6000][1024] + L0|L1 fp32 [2][64][1500]
#define PART_BYTE_OFF 32964608u
#define WS3_NEED_BYTES (82884608ull)

typedef __attribute__((ext_vector_type(8))) short short8v;    // 8 bf16
typedef __attribute__((ext_vector_type(4))) float f32x4;
typedef __attribute__((ext_vector_type(16))) float f32x16;
typedef __attribute__((ext_vector_type(4))) unsigned short ushort4v;

__device__ __forceinline__ unsigned short f2bf(float f) {
    union { float f; unsigned int i; } c; c.f = f;
    return (unsigned short)((c.i + 0x7FFFu + ((c.i >> 16) & 1u)) >> 16);
}
__device__ __forceinline__ unsigned int cvt_pk_bf16(float a, float b) {
    unsigned int r;
    asm("v_cvt_pk_bf16_f32 %0, %1, %2" : "=v"(r) : "v"(a), "v"(b));
    return r;
}
// v_permlane32_swap_b32: a'[l] = l<32 ? a[l] : b[l-32]; b'[l] = l<32 ? a[l+32] : b[l]
__device__ __forceinline__ void perml32(unsigned int &a, unsigned int &b) {
    asm("v_permlane32_swap_b32 %0, %1" : "+v"(a), "+v"(b));
}

// Swizzled short-index into [R][64] bf16 LDS tiles (proven r4-r9).
__device__ __forceinline__ int swz(int row, int col) {
    return (row << 6) + ((((col >> 3) ^ row) & 7) << 3) + (col & 7);
}
// Folded swizzle for attn K/V tiles (proven r6-r9).
__device__ __forceinline__ int swzf(int r, int d) {
    int row = r >> 1;
    int cs = ((r & 1) << 3) | (d >> 3);
    return row * 128 + ((cs ^ (row & 15)) << 3) + (d & 7);
}

__device__ __forceinline__ short8v pack8(const float* x) {
    union { unsigned int u[4]; short8v v; } r;
    r.u[0] = cvt_pk_bf16(x[0], x[1]);
    r.u[1] = cvt_pk_bf16(x[2], x[3]);
    r.u[2] = cvt_pk_bf16(x[4], x[5]);
    r.u[3] = cvt_pk_bf16(x[6], x[7]);
    return r.v;
}

// async global->LDS, 16B per lane; LDS dest wave-uniform base + lane*16.
__device__ __forceinline__ void gload16(const unsigned short* g,
                                        unsigned short* l) {
    __builtin_amdgcn_global_load_lds(
        (const __attribute__((address_space(1))) unsigned int*)(g),
        (__attribute__((address_space(3))) unsigned int*)(l), 16, 0, 0);
}

// ===========================================================================
// fp32 -> bf16 conversion of X, Wk, Wv, Wq(*QSC), Wo into ws. 8 elems/thread.
// ===========================================================================
__global__ __launch_bounds__(256) void cvt_kernel(
    const float* __restrict__ X,  const float* __restrict__ Wk,
    const float* __restrict__ Wv, const float* __restrict__ Wq,
    const float* __restrict__ Wo, unsigned short* __restrict__ ws)
{
    size_t w = ((size_t)blockIdx.x * 256 + threadIdx.x) * 8;
    const float* s; unsigned short* d; float sc = 1.0f;
    if (w < 6144000u)      { s = X  + w;             d = ws + XB_OFF + w; }
    else if (w < 7192576u) { s = Wk + (w - 6144000u); d = ws + WB_OFF + (w - 6144000u); }
    else if (w < 8241152u) { s = Wv + (w - 7192576u); d = ws + WB_OFF + 1048576u + (w - 7192576u); }
    else if (w < 9289728u) { s = Wq + (w - 8241152u); d = ws + WB_OFF + 2097152u + (w - 8241152u); sc = QSC; }
    else                   { s = Wo + (w - 9289728u); d = ws + WOB_OFF + (w - 9289728u); }
    float t[8];
    *(float4*)t = *(const float4*)s;
    *(float4*)(t + 4) = *(const float4*)(s + 4);
#pragma unroll
    for (int i = 0; i < 8; ++i) t[i] *= sc;
    *(short8v*)d = pack8(t);
}

// ---------------------------------------------------------------------------
// m97-structure 128x128x1024 GEMM body (proven r8): single-buffer LDS,
// global_load_lds with pre-swizzled global source, 2 barriers/step.
// ---------------------------------------------------------------------------
__device__ __forceinline__ void gemm128b(
    const unsigned short* __restrict__ Arow,
    const unsigned short* __restrict__ Brow,
    unsigned short* As, unsigned short* Bs, int tid, f32x4 acc[4][4])
{
    const int lane = tid & 63, wid = tid >> 6;
    const int wm = tid >> 7, wn = (tid >> 6) & 1;
    for (int k0 = 0; k0 < E; k0 += 64) {
#pragma unroll
        for (int i = 0; i < 4; ++i) {
            int row = wid * 32 + i * 8 + (lane >> 3);
            int sl = (lane & 7) ^ (row & 7);            // inverse-swz source
            unsigned short* lbase = As + (wid * 32 + i * 8) * 64;
            gload16(Arow + (size_t)row * E + k0 + sl * 8, lbase);
            unsigned short* lbase2 = Bs + (wid * 32 + i * 8) * 64;
            gload16(Brow + (size_t)row * E + k0 + sl * 8, lbase2);
        }
        __syncthreads();          // vmcnt(0) drain: tiles ready
#pragma unroll
        for (int kk = 0; kk < 64; kk += 32) {
            short8v afr[4], bfr[4];
#pragma unroll
            for (int m = 0; m < 4; ++m)
                afr[m] = *(const short8v*)(As + swz(wm * 64 + m * 16 + (lane & 15),
                                                    kk + (lane >> 4) * 8));
#pragma unroll
            for (int n = 0; n < 4; ++n)
                bfr[n] = *(const short8v*)(Bs + swz(wn * 64 + n * 16 + (lane & 15),
                                                    kk + (lane >> 4) * 8));
            __builtin_amdgcn_s_setprio(1);
#pragma unroll
            for (int m = 0; m < 4; ++m)
#pragma unroll
                for (int n = 0; n < 4; ++n)
                    acc[m][n] = __builtin_amdgcn_mfma_f32_16x16x32_bf16(
                        afr[m], bfr[n], acc[m][n], 0, 0, 0);
            __builtin_amdgcn_s_setprio(0);
        }
        __syncthreads();          // frag reads done before next stage
    }
}

// Projections (fast): nb 0-7: K; 8-15: V(+bv, ->V^T); 16-23: Q(+bq*QSC).
__global__ __launch_bounds__(256) void proj_fast(
    const unsigned short* __restrict__ Xb, const unsigned short* __restrict__ Wb,
    const float* __restrict__ bv, const float* __restrict__ bq,
    unsigned short* __restrict__ Kb, unsigned short* __restrict__ Vt,
    unsigned short* __restrict__ Qa)
{
    __shared__ unsigned short As[128 * 64], Bs[128 * 64];
    const int sid = blockIdx.x;
    const int nid = (sid & 7) * 141 + (sid >> 3);        // T1 XCD-chunked
    const int mb = nid / 24, nb = nid % 24;
    const int z = nb >> 3;
    const size_t m0 = (size_t)mb * 128;
    const int tid = threadIdx.x, lane = tid & 63;
    const int wm = tid >> 7, wn = (tid >> 6) & 1;

    f32x4 acc[4][4];
#pragma unroll
    for (int m = 0; m < 4; ++m)
#pragma unroll
        for (int n = 0; n < 4; ++n)
#pragma unroll
            for (int i = 0; i < 4; ++i) acc[m][n][i] = 0.f;

    gemm128b(Xb + m0 * E, Wb + (size_t)nb * 128 * E, As, Bs, tid, acc);

#pragma unroll
    for (int m = 0; m < 4; ++m) {
        long gi0 = (long)m0 + wm * 64 + m * 16 + (lane >> 4) * 4;
#pragma unroll
        for (int n = 0; n < 4; ++n) {
            int col = (nb & 7) * 128 + wn * 64 + n * 16 + (lane & 15);
            if (z == 0) {
#pragma unroll
                for (int rg = 0; rg < 4; ++rg) {
                    long gi = gi0 + rg;
                    if (gi < M_) Kb[(size_t)gi * E + col] = f2bf(acc[m][n][rg]);
                }
            } else if (z == 2) {
                float bias = bq[col] * QSC;
#pragma unroll
                for (int rg = 0; rg < 4; ++rg) {
                    long gi = gi0 + rg;
                    if (gi < M_)
                        Qa[(size_t)gi * E + col] = f2bf(acc[m][n][rg] + bias);
                }
            } else {
                float bias = bv[col];
                if (gi0 + 3 < M_) {      // quad never crosses batch (SEQ_%4==0)
                    long bb = gi0 / SEQ_, t0 = gi0 % SEQ_;
                    union { unsigned int u[2]; ushort4v v; } pk;
                    pk.u[0] = cvt_pk_bf16(acc[m][n][0] + bias, acc[m][n][1] + bias);
                    pk.u[1] = cvt_pk_bf16(acc[m][n][2] + bias, acc[m][n][3] + bias);
                    *(ushort4v*)(Vt + ((size_t)bb * E + col) * SEQ_ + t0) = pk.v;
                } else {
#pragma unroll
                    for (int rg = 0; rg < 4; ++rg) {
                        long gi = gi0 + rg;
                        if (gi < M_) {
                            long bb = gi / SEQ_, t = gi % SEQ_;
                            Vt[((size_t)bb * E + col) * SEQ_ + t] =
                                f2bf(acc[m][n][rg] + bias);
                        }
                    }
                }
            }
        }
    }
}

// Output projection (fast): A = attn-out bf16 (Qa region), B = Wob bf16.
__global__ __launch_bounds__(256) void oproj_fast(
    const unsigned short* __restrict__ Ab, const unsigned short* __restrict__ Wob,
    const float* __restrict__ bo, float* __restrict__ out)
{
    __shared__ unsigned short As[128 * 64], Bs[128 * 64];
    const int sid = blockIdx.x;
    const int nid = (sid & 7) * 47 + (sid >> 3);         // 376 blocks
    const int mb = nid >> 3, nb = nid & 7;
    const size_t m0 = (size_t)mb * 128;
    const int tid = threadIdx.x, lane = tid & 63;
    const int wm = tid >> 7, wn = (tid >> 6) & 1;

    f32x4 acc[4][4];
#pragma unroll
    for (int m = 0; m < 4; ++m)
#pragma unroll
        for (int n = 0; n < 4; ++n)
#pragma unroll
            for (int i = 0; i < 4; ++i) acc[m][n][i] = 0.f;

    gemm128b(Ab + m0 * E, Wob + (size_t)nb * 128 * E, As, Bs, tid, acc);

#pragma unroll
    for (int m = 0; m < 4; ++m) {
        long gi0 = (long)m0 + wm * 64 + m * 16 + (lane >> 4) * 4;
#pragma unroll
        for (int n = 0; n < 4; ++n) {
            int col = nb * 128 + wn * 64 + n * 16 + (lane & 15);
            float bias = bo[col];
#pragma unroll
            for (int rg = 0; rg < 4; ++rg) {
                long gi = gi0 + rg;
                if (gi < M_) out[(size_t)gi * E + col] = acc[m][n][rg] + bias;
            }
        }
    }
}

// ===========================================================================
// FALLBACK PATH (r7, proven): fp32-reg-staged 128x128 GEMM.
// ===========================================================================
template <bool ABF>
__device__ __forceinline__ void gemm128(
    const float* __restrict__ Af, const unsigned short* __restrict__ Ab,
    size_t arow0, int avalid,
    const float* __restrict__ W, int wrow0,
    unsigned short* As, unsigned short* Bs,
    int tid, f32x4 acc[4][4])
{
    const int lane = tid & 63;
    const int wm = (tid >> 7), wn = (tid >> 6) & 1;
    float4 pA[8]; short8v pAb[4]; float4 pB[8];

    auto loadT = [&](int k0) {
#pragma unroll
        for (int uu = 0; uu < 4; ++uu) {
            int u = tid + uu * 256, row = u >> 3, sl = (u & 7) * 8;
            if constexpr (ABF) {
                short8v t;
#pragma unroll
                for (int i = 0; i < 8; ++i) t[i] = 0;
                if (row < avalid)
                    t = *(const short8v*)(Ab + (arow0 + row) * E + k0 + sl);
                pAb[uu] = t;
            } else {
                float4 x0 = make_float4(0.f, 0.f, 0.f, 0.f), x1 = x0;
                if (row < avalid) {
                    const float* p = Af + (arow0 + row) * (size_t)E + k0 + sl;
                    x0 = *(const float4*)p; x1 = *(const float4*)(p + 4);
                }
                pA[2 * uu] = x0; pA[2 * uu + 1] = x1;
            }
            const float* q = W + (size_t)(wrow0 + row) * E + k0 + sl;
            pB[2 * uu] = *(const float4*)q;
            pB[2 * uu + 1] = *(const float4*)(q + 4);
        }
    };
    auto commitT = [&]() {
#pragma unroll
        for (int uu = 0; uu < 4; ++uu) {
            int u = tid + uu * 256, row = u >> 3, sl = (u & 7) * 8;
            if constexpr (ABF) {
                *(short8v*)(As + swz(row, sl)) = pAb[uu];
            } else {
                float t[8];
                *(float4*)t = pA[2 * uu]; *(float4*)(t + 4) = pA[2 * uu + 1];
                *(short8v*)(As + swz(row, sl)) = pack8(t);
            }
            float t2[8];
            *(float4*)t2 = pB[2 * uu]; *(float4*)(t2 + 4) = pB[2 * uu + 1];
            *(short8v*)(Bs + swz(row, sl)) = pack8(t2);
        }
    };

    loadT(0);
    for (int k0 = 0; k0 < E; k0 += 64) {
        __syncthreads();
        commitT();
        __syncthreads();
        if (k0 + 64 < E) loadT(k0 + 64);
#pragma unroll
        for (int kk = 0; kk < 64; kk += 32) {
            short8v afr[4], bfr[4];
#pragma unroll
            for (int m = 0; m < 4; ++m)
                afr[m] = *(const short8v*)(As + swz(wm * 64 + m * 16 + (lane & 15),
                                                    kk + (lane >> 4) * 8));
#pragma unroll
            for (int n = 0; n < 4; ++n)
                bfr[n] = *(const short8v*)(Bs + swz(wn * 64 + n * 16 + (lane & 15),
                                                    kk + (lane >> 4) * 8));
            __builtin_amdgcn_s_setprio(1);
#pragma unroll
            for (int m = 0; m < 4; ++m)
#pragma unroll
                for (int n = 0; n < 4; ++n)
                    acc[m][n] = __builtin_amdgcn_mfma_f32_16x16x32_bf16(
                        afr[m], bfr[n], acc[m][n], 0, 0, 0);
            __builtin_amdgcn_s_setprio(0);
        }
    }
}

__global__ __launch_bounds__(256, 2) void proj_kernel(
    const float* __restrict__ X, const float* __restrict__ Wk,
    const float* __restrict__ Wv, const float* __restrict__ bv,
    const float* __restrict__ Wq, const float* __restrict__ bq,
    unsigned short* __restrict__ Kb, unsigned short* __restrict__ Vt,
    unsigned short* __restrict__ Qo)
{
    __shared__ unsigned short As[128 * 64], Bs[128 * 64];
    const int sid = blockIdx.x, cpx = gridDim.x >> 3;
    const int nid = (sid & 7) * cpx + (sid >> 3);
    const int mb = nid / 24, nb = nid % 24;
    const int z = nb >> 3, nbz = nb & 7;
    const size_t m0 = (size_t)mb * 128;
    const int avalid = (M_ - (int)m0) < 128 ? (M_ - (int)m0) : 128;
    const float* W = (z == 0) ? Wk : (z == 1) ? Wv : Wq;

    f32x4 acc[4][4];
#pragma unroll
    for (int m = 0; m < 4; ++m)
#pragma unroll
        for (int n = 0; n < 4; ++n)
#pragma unroll
            for (int i = 0; i < 4; ++i) acc[m][n][i] = 0.f;

    gemm128<false>(X, nullptr, m0, avalid, W, nbz * 128, As, Bs, threadIdx.x, acc);

    const int tid = threadIdx.x, lane = tid & 63;
    const int wm = (tid >> 7), wn = (tid >> 6) & 1;
#pragma unroll
    for (int m = 0; m < 4; ++m) {
        long gi0 = (long)m0 + wm * 64 + m * 16 + (lane >> 4) * 4;
#pragma unroll
        for (int n = 0; n < 4; ++n) {
            int col = nbz * 128 + wn * 64 + n * 16 + (lane & 15);
            if (z == 0) {
#pragma unroll
                for (int rg = 0; rg < 4; ++rg) {
                    long gi = gi0 + rg;
                    if (gi < M_) Kb[(size_t)gi * E + col] = f2bf(acc[m][n][rg]);
                }
            } else if (z == 2) {
                float bias = bq[col];
#pragma unroll
                for (int rg = 0; rg < 4; ++rg) {
                    long gi = gi0 + rg;
                    if (gi < M_)
                        Qo[(size_t)gi * E + col] = f2bf((acc[m][n][rg] + bias) * QSC);
                }
            } else {
                float bias = bv[col];
                if (gi0 + 3 < M_) {
                    long bb = gi0 / SEQ_, t0 = gi0 % SEQ_;
                    union { unsigned int u[2]; ushort4v v; } pk;
                    pk.u[0] = cvt_pk_bf16(acc[m][n][0] + bias, acc[m][n][1] + bias);
                    pk.u[1] = cvt_pk_bf16(acc[m][n][2] + bias, acc[m][n][3] + bias);
                    *(ushort4v*)(Vt + ((size_t)bb * E + col) * SEQ_ + t0) = pk.v;
                } else {
#pragma unroll
                    for (int rg = 0; rg < 4; ++rg) {
                        long gi = gi0 + rg;
                        if (gi < M_) {
                            long bb = gi / SEQ_, t = gi % SEQ_;
                            Vt[((size_t)bb * E + col) * SEQ_ + t] =
                                f2bf(acc[m][n][rg] + bias);
                        }
                    }
                }
            }
        }
    }
}

__global__ __launch_bounds__(256, 2) void oproj_kernel(
    const unsigned short* __restrict__ Ab, const float* __restrict__ Wo,
    const float* __restrict__ bo, float* __restrict__ out)
{
    __shared__ unsigned short As[128 * 64], Bs[128 * 64];
    const int sid = blockIdx.x, cpx = gridDim.x >> 3;
    const int nid = (sid & 7) * cpx + (sid >> 3);
    const int mb = nid >> 3, nb = nid & 7;
    const size_t m0 = (size_t)mb * 128;
    const int avalid = (M_ - (int)m0) < 128 ? (M_ - (int)m0) : 128;

    f32x4 acc[4][4];
#pragma unroll
    for (int m = 0; m < 4; ++m)
#pragma unroll
        for (int n = 0; n < 4; ++n)
#pragma unroll
            for (int i = 0; i < 4; ++i) acc[m][n][i] = 0.f;

    gemm128<true>(nullptr, Ab, m0, avalid, Wo, nb * 128, As, Bs, threadIdx.x, acc);

    const int tid = threadIdx.x, lane = tid & 63;
    const int wm = (tid >> 7), wn = (tid >> 6) & 1;
#pragma unroll
    for (int m = 0; m < 4; ++m) {
        long gi0 = (long)m0 + wm * 64 + m * 16 + (lane >> 4) * 4;
#pragma unroll
        for (int n = 0; n < 4; ++n) {
            int col = nb * 128 + wn * 64 + n * 16 + (lane & 15);
            float bias = bo[col];
#pragma unroll
            for (int rg = 0; rg < 4; ++rg) {
                long gi = gi0 + rg;
                if (gi < M_) out[(size_t)gi * E + col] = acc[m][n][rg] + bias;
            }
        }
    }
}

// ===========================================================================
// TIER-3 attention: K-split x2. Each block = 128 q-rows of one (b,h) over
// HALF the keys (12 tiles). Single-buffer LDS (16KB) -> 6 blocks/CU, 24
// waves/CU (vs 12 grid-capped before). Writes UNNORMALIZED fp32 partial O
// and lsum; combine kernel normalizes. Core math identical to r9 (proven).
// ===========================================================================
__global__ __launch_bounds__(256, 4) void attn_ks(
    const unsigned short* __restrict__ Kb,
    const unsigned short* __restrict__ Vt,
    const unsigned short* __restrict__ Qa,
    float* __restrict__ Pp, float* __restrict__ Lp)
{
    __shared__ unsigned short ks[32 * 128], vs[32 * 128];
    const int sid = blockIdx.x;
    const int nid = (sid & 7) * 192 + (sid >> 3);   // 1536 blocks, 192/XCD
    const int bh = nid / 24, rest = nid % 24;
    const int qb = rest >> 1, kh = rest & 1;
    const int b = bh >> 4, hh = bh & 15;
    const int tid = threadIdx.x, lane = tid & 63, wz = tid >> 6;
    const int c = lane & 31, g2 = lane >> 5;
    const int q0 = qb * 128 + wz * 32;

    const unsigned short* kbase = Kb + (size_t)b * SEQ_ * E + hh * 64;
    const unsigned short* vbase = Vt + ((size_t)b * E + hh * 64) * SEQ_;
    float* Po = Pp + (size_t)kh * SZE;
    float* Lo = Lp + (size_t)kh * (64 * SEQ_);

    short8v kreg[2];
    ushort4v vreg[4];
    auto loadK = [&](int kt0) {
#pragma unroll
        for (int uu = 0; uu < 2; ++uu) {
            int u = tid + uu * 256, key = u >> 3, slot = (u & 7) * 8;
            short8v t;
#pragma unroll
            for (int i = 0; i < 8; ++i) t[i] = 0;
            int gk = kt0 + key;
            if (gk < SEQ_) t = *(const short8v*)(kbase + (size_t)gk * E + slot);
            kreg[uu] = t;
        }
    };
    auto loadV = [&](int kt0) {
#pragma unroll
        for (int uu = 0; uu < 4; ++uu) {
            int u = tid + uu * 256, d = u >> 4, q4 = (u & 15) * 4;
            ushort4v t; t[0] = t[1] = t[2] = t[3] = 0;
            int col = kt0 + q4, rem = SEQ_ - col;
            const unsigned short* src = vbase + (size_t)d * SEQ_ + col;
            if (rem >= 4) t = *(const ushort4v*)src;
            else { for (int e2 = 0; e2 < 4; ++e2) if (e2 < rem) t[e2] = src[e2]; }
            vreg[uu] = t;
        }
    };
    auto commitKV = [&]() {
#pragma unroll
        for (int uu = 0; uu < 2; ++uu) {
            int u = tid + uu * 256;
            *(short8v*)(ks + swzf(u >> 3, (u & 7) * 8)) = kreg[uu];
        }
#pragma unroll
        for (int uu = 0; uu < 4; ++uu) {
            int u = tid + uu * 256;
            *(ushort4v*)(vs + swzf(u >> 4, (u & 15) * 4)) = vreg[uu];
        }
    };

    const int tbeg = kh * 12, tend = tbeg + 12;
    loadK(tbeg * 64); loadV(tbeg * 64);

    // Q B-frags in registers: qf[t] holds q=q0+c, d = t*16 + 8*g2 + 0..7
    short8v qf[4];
    {
        int qr = q0 + c;
        bool ok = qr < SEQ_;
        const unsigned short* qp = Qa + ((size_t)b * SEQ_ + qr) * E + hh * 64 + 8 * g2;
#pragma unroll
        for (int t = 0; t < 4; ++t) {
            short8v zv;
#pragma unroll
            for (int i = 0; i < 8; ++i) zv[i] = 0;
            if (ok) zv = *(const short8v*)(qp + t * 16);
            qf[t] = zv;
        }
    }

    f32x16 o0, o1;
#pragma unroll
    for (int i = 0; i < 16; ++i) { o0[i] = 0.f; o1[i] = 0.f; }
    float lsum = 0.f;

    for (int it = tbeg; it < tend; ++it) {
        const int kt0 = it * 64;
        __syncthreads();            // prev tile's frag reads done
        commitKV();
        __syncthreads();            // tile ready
        if (it + 1 < tend) { loadK(kt0 + 64); loadV(kt0 + 64); }  // overlap
        const bool tail = (kt0 + 64 > SEQ_);

#pragma unroll
        for (int nt = 0; nt < 2; ++nt) {
            // S^T = mfma(K, Q): lane holds q=c, keys=(reg&3)+8*(reg>>2)+4*g2
            f32x16 s;
#pragma unroll
            for (int i = 0; i < 16; ++i) s[i] = 0.f;
            __builtin_amdgcn_s_setprio(1);
#pragma unroll
            for (int t = 0; t < 4; ++t) {
                short8v af = *(const short8v*)(ks + swzf(nt * 32 + c, t * 16 + 8 * g2));
                s = __builtin_amdgcn_mfma_f32_32x32x16_bf16(af, qf[t], s, 0, 0, 0);
            }
            __builtin_amdgcn_s_setprio(0);
            if (tail) {
#pragma unroll
                for (int r = 0; r < 16; ++r) {
                    int key = kt0 + nt * 32 + (r & 3) + 8 * (r >> 2) + 4 * g2;
                    if (key >= SEQ_) s[r] = -1e30f;   // exp2 -> 0
                }
            }
            // max-free softmax fused with pack (scores |s|~O(3))
            unsigned int pk[8];
            float ls0 = 0.f, ls1 = 0.f;
#pragma unroll
            for (int h = 0; h < 8; ++h) {
                float p0 = __builtin_amdgcn_exp2f(s[2 * h]);
                float p1 = __builtin_amdgcn_exp2f(s[2 * h + 1]);
                if (h & 1) ls1 += p0 + p1; else ls0 += p0 + p1;
                pk[h] = cvt_pk_bf16(p0, p1);
            }
            lsum += ls0 + ls1;
            perml32(pk[0], pk[2]); perml32(pk[1], pk[3]);
            perml32(pk[4], pk[6]); perml32(pk[5], pk[7]);
            // PV
            __builtin_amdgcn_s_setprio(1);
#pragma unroll
            for (int tau = 0; tau < 2; ++tau) {
                union { unsigned int w[4]; short8v v; } pa;
                pa.w[0] = pk[4 * tau + 0];
                pa.w[1] = pk[4 * tau + 1];
                pa.w[2] = pk[4 * tau + 2];
                pa.w[3] = pk[4 * tau + 3];
                int t = nt * 2 + tau;
                short8v vb0 = *(const short8v*)(vs + swzf(0 + c, t * 16 + 8 * g2));
                short8v vb1 = *(const short8v*)(vs + swzf(32 + c, t * 16 + 8 * g2));
                o0 = __builtin_amdgcn_mfma_f32_32x32x16_bf16(pa.v, vb0, o0, 0, 0, 0);
                o1 = __builtin_amdgcn_mfma_f32_32x32x16_bf16(pa.v, vb1, o1, 0, 0, 0);
            }
            __builtin_amdgcn_s_setprio(0);
        }
    }

    // epilogue: UNNORMALIZED partials. lsum: combine g2 halves; lane<32 has q=c
    lsum += __shfl_xor(lsum, 32, 64);
    if (lane < 32) {
        int tq = q0 + c;
        if (tq < SEQ_) Lo[(size_t)bh * SEQ_ + tq] = lsum;
    }
#pragma unroll
    for (int r = 0; r < 16; ++r) {
        int ql = (r & 3) + 8 * (r >> 2) + 4 * g2;
        int tq = q0 + ql;
        if (tq < SEQ_) {
            float* op = Po + ((size_t)b * SEQ_ + tq) * E + hh * 64;
            op[c] = o0[r];
            op[32 + c] = o1[r];
        }
    }
}

// combine: Qa = (P0 + P1) / (L0 + L1), bf16. 8 elems/thread, 3000 blocks.
__global__ __launch_bounds__(256) void combine_kernel(
    const float* __restrict__ Pp, const float* __restrict__ Lp,
    unsigned short* __restrict__ Qa)
{
    size_t i8 = ((size_t)blockIdx.x * 256 + threadIdx.x) * 8;
    size_t row = i8 >> 10;
    int e = (int)(i8 & 1023);
    int bh = (int)(row / SEQ_) * 16 + (e >> 6);
    int t = (int)(row % SEQ_);
    size_t li = (size_t)bh * SEQ_ + t;
    float inv = 1.0f / (Lp[li] + Lp[(size_t)64 * SEQ_ + li]);
    const float* p0 = Pp + i8;
    const float* p1 = Pp + SZE + i8;
    float t0[8], t1[8], r8[8];
    *(float4*)t0 = *(const float4*)p0; *(float4*)(t0 + 4) = *(const float4*)(p0 + 4);
    *(float4*)t1 = *(const float4*)p1; *(float4*)(t1 + 4) = *(const float4*)(p1 + 4);
#pragma unroll
    for (int i = 0; i < 8; ++i) r8[i] = (t0[i] + t1[i]) * inv;
    *(short8v*)(Qa + i8) = pack8(r8);
}

// ===========================================================================
// TIER-2 attention (r9, proven 83us): double-buffer, normalizes in-kernel,
// overwrites Qa in place.
// ===========================================================================
__global__ __launch_bounds__(256, 4) void attn_kernel(
    const unsigned short* __restrict__ Kb,
    const unsigned short* __restrict__ Vt,
    unsigned short* __restrict__ Qa)
{
    __shared__ unsigned short ks[2][32 * 128], vs[2][32 * 128];
    const int sid = blockIdx.x;
    const int nid = (sid & 7) * 96 + (sid >> 3);
    const int bh = nid / 12, qb = nid % 12;
    const int b = bh >> 4, hh = bh & 15;
    const int tid = threadIdx.x, lane = tid & 63, wz = tid >> 6;
    const int c = lane & 31, g2 = lane >> 5;
    const int q0 = qb * 128 + wz * 32;

    const unsigned short* kbase = Kb + (size_t)b * SEQ_ * E + hh * 64;
    const unsigned short* vbase = Vt + ((size_t)b * E + hh * 64) * SEQ_;

    short8v kreg[2];
    ushort4v vreg[4];
    auto loadK = [&](int kt0) {
#pragma unroll
        for (int uu = 0; uu < 2; ++uu) {
            int u = tid + uu * 256, key = u >> 3, slot = (u & 7) * 8;
            short8v t;
#pragma unroll
            for (int i = 0; i < 8; ++i) t[i] = 0;
            int gk = kt0 + key;
            if (gk < SEQ_) t = *(const short8v*)(kbase + (size_t)gk * E + slot);
            kreg[uu] = t;
        }
    };
    auto loadV = [&](int kt0) {
#pragma unroll
        for (int uu = 0; uu < 4; ++uu) {
            int u = tid + uu * 256, d = u >> 4, q4 = (u & 15) * 4;
            ushort4v t; t[0] = t[1] = t[2] = t[3] = 0;
            int col = kt0 + q4, rem = SEQ_ - col;
            const unsigned short* src = vbase + (size_t)d * SEQ_ + col;
            if (rem >= 4) t = *(const ushort4v*)src;
            else { for (int e2 = 0; e2 < 4; ++e2) if (e2 < rem) t[e2] = src[e2]; }
            vreg[uu] = t;
        }
    };
    auto commitKV = [&](unsigned short* kd, unsigned short* vd) {
#pragma unroll
        for (int uu = 0; uu < 2; ++uu) {
            int u = tid + uu * 256;
            *(short8v*)(kd + swzf(u >> 3, (u & 7) * 8)) = kreg[uu];
        }
#pragma unroll
        for (int uu = 0; uu < 4; ++uu) {
            int u = tid + uu * 256;
            *(ushort4v*)(vd + swzf(u >> 4, (u & 15) * 4)) = vreg[uu];
        }
    };

    loadK(0); loadV(0);

    short8v qf[4];
    {
        int qr = q0 + c;
        bool ok = qr < SEQ_;
        const unsigned short* qp = Qa + ((size_t)b * SEQ_ + qr) * E + hh * 64 + 8 * g2;
#pragma unroll
        for (int t = 0; t < 4; ++t) {
            short8v zv;
#pragma unroll
            for (int i = 0; i < 8; ++i) zv[i] = 0;
            if (ok) zv = *(const short8v*)(qp + t * 16);
            qf[t] = zv;
        }
    }

    f32x16 o0, o1;
#pragma unroll
    for (int i = 0; i < 16; ++i) { o0[i] = 0.f; o1[i] = 0.f; }
    float lsum = 0.f;

    commitKV(ks[0], vs[0]);
    __syncthreads();
    loadK(64); loadV(64);

    const int NT = (SEQ_ + 63) / 64;     // 24
    for (int it = 0; it < NT; ++it) {
        const int kt0 = it * 64;
        const unsigned short* kcur = ks[it & 1];
        const unsigned short* vcur = vs[it & 1];
        const bool tail = (kt0 + 64 > SEQ_);

#pragma unroll
        for (int nt = 0; nt < 2; ++nt) {
            f32x16 s;
#pragma unroll
            for (int i = 0; i < 16; ++i) s[i] = 0.f;
            __builtin_amdgcn_s_setprio(1);
#pragma unroll
            for (int t = 0; t < 4; ++t) {
                short8v af = *(const short8v*)(kcur + swzf(nt * 32 + c, t * 16 + 8 * g2));
                s = __builtin_amdgcn_mfma_f32_32x32x16_bf16(af, qf[t], s, 0, 0, 0);
            }
            __builtin_amdgcn_s_setprio(0);
            if (tail) {
#pragma unroll
                for (int r = 0; r < 16; ++r) {
                    int key = kt0 + nt * 32 + (r & 3) + 8 * (r >> 2) + 4 * g2;
                    if (key >= SEQ_) s[r] = -1e30f;
                }
            }
            unsigned int pk[8];
            float ls0 = 0.f, ls1 = 0.f;
#pragma unroll
            for (int h = 0; h < 8; ++h) {
                float p0 = __builtin_amdgcn_exp2f(s[2 * h]);
                float p1 = __builtin_amdgcn_exp2f(s[2 * h + 1]);
                if (h & 1) ls1 += p0 + p1; else ls0 += p0 + p1;
                pk[h] = cvt_pk_bf16(p0, p1);
            }
            lsum += ls0 + ls1;
            perml32(pk[0], pk[2]); perml32(pk[1], pk[3]);
            perml32(pk[4], pk[6]); perml32(pk[5], pk[7]);
            __builtin_amdgcn_s_setprio(1);
#pragma unroll
            for (int tau = 0; tau < 2; ++tau) {
                union { unsigned int w[4]; short8v v; } pa;
                pa.w[0] = pk[4 * tau + 0];
                pa.w[1] = pk[4 * tau + 1];
                pa.w[2] = pk[4 * tau + 2];
                pa.w[3] = pk[4 * tau + 3];
                int t = nt * 2 + tau;
                short8v vb0 = *(const short8v*)(vcur + swzf(0 + c, t * 16 + 8 * g2));
                short8v vb1 = *(const short8v*)(vcur + swzf(32 + c, t * 16 + 8 * g2));
                o0 = __builtin_amdgcn_mfma_f32_32x32x16_bf16(pa.v, vb0, o0, 0, 0, 0);
                o1 = __builtin_amdgcn_mfma_f32_32x32x16_bf16(pa.v, vb1, o1, 0, 0, 0);
            }
            __builtin_amdgcn_s_setprio(0);
        }

        if (it + 1 < NT) {
            commitKV(ks[(it + 1) & 1], vs[(it + 1) & 1]);
            __syncthreads();
            if (it + 2 < NT) { loadK(kt0 + 128); loadV(kt0 + 128); }
        }
    }

    lsum += __shfl_xor(lsum, 32, 64);
    __syncthreads();
    float* lf = (float*)ks[0] + wz * 32;
    if (lane < 32) lf[c] = 1.0f / lsum;
#pragma unroll
    for (int r = 0; r < 16; ++r) {
        int ql = (r & 3) + 8 * (r >> 2) + 4 * g2;
        int tq = q0 + ql;
        if (tq < SEQ_) {
            float inv = lf[ql];
            unsigned short* op = Qa + ((size_t)b * SEQ_ + tq) * E + hh * 64;
            op[c] = f2bf(o0[r] * inv);
            op[32 + c] = f2bf(o1[r] * inv);
        }
    }
}

extern "C" void kernel_launch(void* const* d_in, const int* in_sizes, int n_in,
                              void* d_out, int out_size, void* d_ws, size_t ws_size,
                              hipStream_t stream) {
    const float* hs = (const float*)d_in[0];
    const float* Wq = (const float*)d_in[1];
    const float* bq = (const float*)d_in[2];
    const float* Wk = (const float*)d_in[3];
    const float* Wv = (const float*)d_in[4];
    const float* bv = (const float*)d_in[5];
    const float* Wo = (const float*)d_in[6];
    const float* bo = (const float*)d_in[7];

    // d_out hosts K bf16 [6000][1024] | V^T bf16 [4][1024][1500] (fully
    // rewritten by oproj at the end). ws: Qa bf16 + bf16 operand cache
    // (+ fp32 partials on tier-3).
    unsigned short* Kb = (unsigned short*)d_out;
    unsigned short* Vt = (unsigned short*)d_out + SZE;
    unsigned short* ws = (unsigned short*)d_ws;
    unsigned short* Qa = ws + QA_OFF;
    float* out = (float*)d_out;

    if (ws_size >= WS3_NEED_BYTES) {
        // tier-3: K-split attention with fp32 partial combine
        float* Pf = (float*)((char*)d_ws + PART_BYTE_OFF);
        float* Lf = Pf + 2 * SZE;
        cvt_kernel<<<dim3(5048), 256, 0, stream>>>(hs, Wk, Wv, Wq, Wo, ws);
        proj_fast<<<dim3(1128), 256, 0, stream>>>(ws + XB_OFF, ws + WB_OFF,
                                                  bv, bq, Kb, Vt, Qa);
        attn_ks<<<dim3(1536), 256, 0, stream>>>(Kb, Vt, Qa, Pf, Lf);
        combine_kernel<<<dim3(3000), 256, 0, stream>>>(Pf, Lf, Qa);
        oproj_fast<<<dim3(376), 256, 0, stream>>>(Qa, ws + WOB_OFF, bo, out);
    } else if (ws_size >= WS_NEED_BYTES) {
        // tier-2 (r9, proven)
        cvt_kernel<<<dim3(5048), 256, 0, stream>>>(hs, Wk, Wv, Wq, Wo, ws);
        proj_fast<<<dim3(1128), 256, 0, stream>>>(ws + XB_OFF, ws + WB_OFF,
                                                  bv, bq, Kb, Vt, Qa);
        attn_kernel<<<dim3(768), 256, 0, stream>>>(Kb, Vt, Qa);
        oproj_fast<<<dim3(376), 256, 0, stream>>>(Qa, ws + WOB_OFF, bo, out);
    } else {
        // tier-1 fallback (r7, proven)
        proj_kernel<<<dim3(47 * 24), 256, 0, stream>>>(hs, Wk, Wv, bv, Wq, bq,
                                                       Kb, Vt, Qa);
        attn_kernel<<<dim3(768), 256, 0, stream>>>(Kb, Vt, Qa);
        oproj_kernel<<<dim3(47 * 8), 256, 0, stream>>>(Qa, Wo, bo, out);
    }
}

// Round 11
// 195.817 us; speedup vs baseline: 1.6094x; 1.6094x over previous
//
#include <hip/hip_runtime.h>
#include <math.h>

#define E 1024
#define NH 16
#define HD 64
#define BSZ_ 4
#define SEQ_ 1500
#define M_ (BSZ_ * SEQ_)                 // 6000
#define SZE ((size_t)M_ * (size_t)E)     // 6,144,000
#define QSC (0.125f * 1.44269504f)       // fold log2e: P = exp2(s)

// ws layout (ushort offsets), fast path:
#define QA_OFF  0u                        // Q / attn-out bf16 [6000][1024]
#define XB_OFF  6144000u                  // X bf16 [6000][1024]
#define WB_OFF  12288000u                 // [Wk;Wv;Wq*QSC] bf16 [3072][1024]
#define WOB_OFF 15433728u                 // Wo bf16 [1024][1024]
#define WS_NEED_BYTES ((size_t)(16482304u) * 2u)          // 32,964,608

typedef __attribute__((ext_vector_type(8))) short short8v;    // 8 bf16
typedef __attribute__((ext_vector_type(4))) float f32x4;
typedef __attribute__((ext_vector_type(16))) float f32x16;
typedef __attribute__((ext_vector_type(4))) unsigned short ushort4v;

__device__ __forceinline__ unsigned short f2bf(float f) {
    union { float f; unsigned int i; } c; c.f = f;
    return (unsigned short)((c.i + 0x7FFFu + ((c.i >> 16) & 1u)) >> 16);
}
__device__ __forceinline__ unsigned int cvt_pk_bf16(float a, float b) {
    unsigned int r;
    asm("v_cvt_pk_bf16_f32 %0, %1, %2" : "=v"(r) : "v"(a), "v"(b));
    return r;
}
// v_permlane32_swap_b32: a'[l] = l<32 ? a[l] : b[l-32]; b'[l] = l<32 ? a[l+32] : b[l]
__device__ __forceinline__ void perml32(unsigned int &a, unsigned int &b) {
    asm("v_permlane32_swap_b32 %0, %1" : "+v"(a), "+v"(b));
}

// Swizzled short-index into [R][64] bf16 LDS tiles (proven r4-r9).
__device__ __forceinline__ int swz(int row, int col) {
    return (row << 6) + ((((col >> 3) ^ row) & 7) << 3) + (col & 7);
}
// Folded swizzle for attn K/V tiles (proven r6-r9).
__device__ __forceinline__ int swzf(int r, int d) {
    int row = r >> 1;
    int cs = ((r & 1) << 3) | (d >> 3);
    return row * 128 + ((cs ^ (row & 15)) << 3) + (d & 7);
}

__device__ __forceinline__ short8v pack8(const float* x) {
    union { unsigned int u[4]; short8v v; } r;
    r.u[0] = cvt_pk_bf16(x[0], x[1]);
    r.u[1] = cvt_pk_bf16(x[2], x[3]);
    r.u[2] = cvt_pk_bf16(x[4], x[5]);
    r.u[3] = cvt_pk_bf16(x[6], x[7]);
    return r.v;
}

// async global->LDS, 16B per lane; LDS dest wave-uniform base + lane*16.
__device__ __forceinline__ void gload16(const unsigned short* g,
                                        unsigned short* l) {
    __builtin_amdgcn_global_load_lds(
        (const __attribute__((address_space(1))) unsigned int*)(g),
        (__attribute__((address_space(3))) unsigned int*)(l), 16, 0, 0);
}

// ===========================================================================
// fp32 -> bf16 conversion of X, Wk, Wv, Wq(*QSC), Wo into ws. 8 elems/thread.
// ===========================================================================
__global__ __launch_bounds__(256) void cvt_kernel(
    const float* __restrict__ X,  const float* __restrict__ Wk,
    const float* __restrict__ Wv, const float* __restrict__ Wq,
    const float* __restrict__ Wo, unsigned short* __restrict__ ws)
{
    size_t w = ((size_t)blockIdx.x * 256 + threadIdx.x) * 8;
    const float* s; unsigned short* d; float sc = 1.0f;
    if (w < 6144000u)      { s = X  + w;             d = ws + XB_OFF + w; }
    else if (w < 7192576u) { s = Wk + (w - 6144000u); d = ws + WB_OFF + (w - 6144000u); }
    else if (w < 8241152u) { s = Wv + (w - 7192576u); d = ws + WB_OFF + 1048576u + (w - 7192576u); }
    else if (w < 9289728u) { s = Wq + (w - 8241152u); d = ws + WB_OFF + 2097152u + (w - 8241152u); sc = QSC; }
    else                   { s = Wo + (w - 9289728u); d = ws + WOB_OFF + (w - 9289728u); }
    float t[8];
    *(float4*)t = *(const float4*)s;
    *(float4*)(t + 4) = *(const float4*)(s + 4);
#pragma unroll
    for (int i = 0; i < 8; ++i) t[i] *= sc;
    *(short8v*)d = pack8(t);
}

// ---------------------------------------------------------------------------
// m97-structure 128x128x1024 GEMM body (proven r8): single-buffer LDS,
// global_load_lds with pre-swizzled global source, 2 barriers/step.
// ---------------------------------------------------------------------------
__device__ __forceinline__ void gemm128b(
    const unsigned short* __restrict__ Arow,
    const unsigned short* __restrict__ Brow,
    unsigned short* As, unsigned short* Bs, int tid, f32x4 acc[4][4])
{
    const int lane = tid & 63, wid = tid >> 6;
    const int wm = tid >> 7, wn = (tid >> 6) & 1;
    for (int k0 = 0; k0 < E; k0 += 64) {
#pragma unroll
        for (int i = 0; i < 4; ++i) {
            int row = wid * 32 + i * 8 + (lane >> 3);
            int sl = (lane & 7) ^ (row & 7);            // inverse-swz source
            unsigned short* lbase = As + (wid * 32 + i * 8) * 64;
            gload16(Arow + (size_t)row * E + k0 + sl * 8, lbase);
            unsigned short* lbase2 = Bs + (wid * 32 + i * 8) * 64;
            gload16(Brow + (size_t)row * E + k0 + sl * 8, lbase2);
        }
        __syncthreads();          // vmcnt(0) drain: tiles ready
#pragma unroll
        for (int kk = 0; kk < 64; kk += 32) {
            short8v afr[4], bfr[4];
#pragma unroll
            for (int m = 0; m < 4; ++m)
                afr[m] = *(const short8v*)(As + swz(wm * 64 + m * 16 + (lane & 15),
                                                    kk + (lane >> 4) * 8));
#pragma unroll
            for (int n = 0; n < 4; ++n)
                bfr[n] = *(const short8v*)(Bs + swz(wn * 64 + n * 16 + (lane & 15),
                                                    kk + (lane >> 4) * 8));
            __builtin_amdgcn_s_setprio(1);
#pragma unroll
            for (int m = 0; m < 4; ++m)
#pragma unroll
                for (int n = 0; n < 4; ++n)
                    acc[m][n] = __builtin_amdgcn_mfma_f32_16x16x32_bf16(
                        afr[m], bfr[n], acc[m][n], 0, 0, 0);
            __builtin_amdgcn_s_setprio(0);
        }
        __syncthreads();          // frag reads done before next stage
    }
}

// Projections (fast): nb 0-7: K; 8-15: V(+bv, ->V^T); 16-23: Q(+bq*QSC).
__global__ __launch_bounds__(256) void proj_fast(
    const unsigned short* __restrict__ Xb, const unsigned short* __restrict__ Wb,
    const float* __restrict__ bv, const float* __restrict__ bq,
    unsigned short* __restrict__ Kb, unsigned short* __restrict__ Vt,
    unsigned short* __restrict__ Qa)
{
    __shared__ unsigned short As[128 * 64], Bs[128 * 64];
    const int sid = blockIdx.x;
    const int nid = (sid & 7) * 141 + (sid >> 3);        // T1 XCD-chunked
    const int mb = nid / 24, nb = nid % 24;
    const int z = nb >> 3;
    const size_t m0 = (size_t)mb * 128;
    const int tid = threadIdx.x, lane = tid & 63;
    const int wm = tid >> 7, wn = (tid >> 6) & 1;

    f32x4 acc[4][4];
#pragma unroll
    for (int m = 0; m < 4; ++m)
#pragma unroll
        for (int n = 0; n < 4; ++n)
#pragma unroll
            for (int i = 0; i < 4; ++i) acc[m][n][i] = 0.f;

    gemm128b(Xb + m0 * E, Wb + (size_t)nb * 128 * E, As, Bs, tid, acc);

#pragma unroll
    for (int m = 0; m < 4; ++m) {
        long gi0 = (long)m0 + wm * 64 + m * 16 + (lane >> 4) * 4;
#pragma unroll
        for (int n = 0; n < 4; ++n) {
            int col = (nb & 7) * 128 + wn * 64 + n * 16 + (lane & 15);
            if (z == 0) {
#pragma unroll
                for (int rg = 0; rg < 4; ++rg) {
                    long gi = gi0 + rg;
                    if (gi < M_) Kb[(size_t)gi * E + col] = f2bf(acc[m][n][rg]);
                }
            } else if (z == 2) {
                float bias = bq[col] * QSC;
#pragma unroll
                for (int rg = 0; rg < 4; ++rg) {
                    long gi = gi0 + rg;
                    if (gi < M_)
                        Qa[(size_t)gi * E + col] = f2bf(acc[m][n][rg] + bias);
                }
            } else {
                float bias = bv[col];
                if (gi0 + 3 < M_) {      // quad never crosses batch (SEQ_%4==0)
                    long bb = gi0 / SEQ_, t0 = gi0 % SEQ_;
                    union { unsigned int u[2]; ushort4v v; } pk;
                    pk.u[0] = cvt_pk_bf16(acc[m][n][0] + bias, acc[m][n][1] + bias);
                    pk.u[1] = cvt_pk_bf16(acc[m][n][2] + bias, acc[m][n][3] + bias);
                    *(ushort4v*)(Vt + ((size_t)bb * E + col) * SEQ_ + t0) = pk.v;
                } else {
#pragma unroll
                    for (int rg = 0; rg < 4; ++rg) {
                        long gi = gi0 + rg;
                        if (gi < M_) {
                            long bb = gi / SEQ_, t = gi % SEQ_;
                            Vt[((size_t)bb * E + col) * SEQ_ + t] =
                                f2bf(acc[m][n][rg] + bias);
                        }
                    }
                }
            }
        }
    }
}

// Output projection (fast): A = attn-out bf16 (Qa region), B = Wob bf16.
__global__ __launch_bounds__(256) void oproj_fast(
    const unsigned short* __restrict__ Ab, const unsigned short* __restrict__ Wob,
    const float* __restrict__ bo, float* __restrict__ out)
{
    __shared__ unsigned short As[128 * 64], Bs[128 * 64];
    const int sid = blockIdx.x;
    const int nid = (sid & 7) * 47 + (sid >> 3);         // 376 blocks
    const int mb = nid >> 3, nb = nid & 7;
    const size_t m0 = (size_t)mb * 128;
    const int tid = threadIdx.x, lane = tid & 63;
    const int wm = tid >> 7, wn = (tid >> 6) & 1;

    f32x4 acc[4][4];
#pragma unroll
    for (int m = 0; m < 4; ++m)
#pragma unroll
        for (int n = 0; n < 4; ++n)
#pragma unroll
            for (int i = 0; i < 4; ++i) acc[m][n][i] = 0.f;

    gemm128b(Ab + m0 * E, Wob + (size_t)nb * 128 * E, As, Bs, tid, acc);

#pragma unroll
    for (int m = 0; m < 4; ++m) {
        long gi0 = (long)m0 + wm * 64 + m * 16 + (lane >> 4) * 4;
#pragma unroll
        for (int n = 0; n < 4; ++n) {
            int col = nb * 128 + wn * 64 + n * 16 + (lane & 15);
            float bias = bo[col];
#pragma unroll
            for (int rg = 0; rg < 4; ++rg) {
                long gi = gi0 + rg;
                if (gi < M_) out[(size_t)gi * E + col] = acc[m][n][rg] + bias;
            }
        }
    }
}

// ===========================================================================
// FALLBACK PATH (r7, proven): fp32-reg-staged 128x128 GEMM.
// ===========================================================================
template <bool ABF>
__device__ __forceinline__ void gemm128(
    const float* __restrict__ Af, const unsigned short* __restrict__ Ab,
    size_t arow0, int avalid,
    const float* __restrict__ W, int wrow0,
    unsigned short* As, unsigned short* Bs,
    int tid, f32x4 acc[4][4])
{
    const int lane = tid & 63;
    const int wm = (tid >> 7), wn = (tid >> 6) & 1;
    float4 pA[8]; short8v pAb[4]; float4 pB[8];

    auto loadT = [&](int k0) {
#pragma unroll
        for (int uu = 0; uu < 4; ++uu) {
            int u = tid + uu * 256, row = u >> 3, sl = (u & 7) * 8;
            if constexpr (ABF) {
                short8v t;
#pragma unroll
                for (int i = 0; i < 8; ++i) t[i] = 0;
                if (row < avalid)
                    t = *(const short8v*)(Ab + (arow0 + row) * E + k0 + sl);
                pAb[uu] = t;
            } else {
                float4 x0 = make_float4(0.f, 0.f, 0.f, 0.f), x1 = x0;
                if (row < avalid) {
                    const float* p = Af + (arow0 + row) * (size_t)E + k0 + sl;
                    x0 = *(const float4*)p; x1 = *(const float4*)(p + 4);
                }
                pA[2 * uu] = x0; pA[2 * uu + 1] = x1;
            }
            const float* q = W + (size_t)(wrow0 + row) * E + k0 + sl;
            pB[2 * uu] = *(const float4*)q;
            pB[2 * uu + 1] = *(const float4*)(q + 4);
        }
    };
    auto commitT = [&]() {
#pragma unroll
        for (int uu = 0; uu < 4; ++uu) {
            int u = tid + uu * 256, row = u >> 3, sl = (u & 7) * 8;
            if constexpr (ABF) {
                *(short8v*)(As + swz(row, sl)) = pAb[uu];
            } else {
                float t[8];
                *(float4*)t = pA[2 * uu]; *(float4*)(t + 4) = pA[2 * uu + 1];
                *(short8v*)(As + swz(row, sl)) = pack8(t);
            }
            float t2[8];
            *(float4*)t2 = pB[2 * uu]; *(float4*)(t2 + 4) = pB[2 * uu + 1];
            *(short8v*)(Bs + swz(row, sl)) = pack8(t2);
        }
    };

    loadT(0);
    for (int k0 = 0; k0 < E; k0 += 64) {
        __syncthreads();
        commitT();
        __syncthreads();
        if (k0 + 64 < E) loadT(k0 + 64);
#pragma unroll
        for (int kk = 0; kk < 64; kk += 32) {
            short8v afr[4], bfr[4];
#pragma unroll
            for (int m = 0; m < 4; ++m)
                afr[m] = *(const short8v*)(As + swz(wm * 64 + m * 16 + (lane & 15),
                                                    kk + (lane >> 4) * 8));
#pragma unroll
            for (int n = 0; n < 4; ++n)
                bfr[n] = *(const short8v*)(Bs + swz(wn * 64 + n * 16 + (lane & 15),
                                                    kk + (lane >> 4) * 8));
            __builtin_amdgcn_s_setprio(1);
#pragma unroll
            for (int m = 0; m < 4; ++m)
#pragma unroll
                for (int n = 0; n < 4; ++n)
                    acc[m][n] = __builtin_amdgcn_mfma_f32_16x16x32_bf16(
                        afr[m], bfr[n], acc[m][n], 0, 0, 0);
            __builtin_amdgcn_s_setprio(0);
        }
    }
}

__global__ __launch_bounds__(256, 2) void proj_kernel(
    const float* __restrict__ X, const float* __restrict__ Wk,
    const float* __restrict__ Wv, const float* __restrict__ bv,
    const float* __restrict__ Wq, const float* __restrict__ bq,
    unsigned short* __restrict__ Kb, unsigned short* __restrict__ Vt,
    unsigned short* __restrict__ Qo)
{
    __shared__ unsigned short As[128 * 64], Bs[128 * 64];
    const int sid = blockIdx.x, cpx = gridDim.x >> 3;
    const int nid = (sid & 7) * cpx + (sid >> 3);
    const int mb = nid / 24, nb = nid % 24;
    const int z = nb >> 3, nbz = nb & 7;
    const size_t m0 = (size_t)mb * 128;
    const int avalid = (M_ - (int)m0) < 128 ? (M_ - (int)m0) : 128;
    const float* W = (z == 0) ? Wk : (z == 1) ? Wv : Wq;

    f32x4 acc[4][4];
#pragma unroll
    for (int m = 0; m < 4; ++m)
#pragma unroll
        for (int n = 0; n < 4; ++n)
#pragma unroll
            for (int i = 0; i < 4; ++i) acc[m][n][i] = 0.f;

    gemm128<false>(X, nullptr, m0, avalid, W, nbz * 128, As, Bs, threadIdx.x, acc);

    const int tid = threadIdx.x, lane = tid & 63;
    const int wm = (tid >> 7), wn = (tid >> 6) & 1;
#pragma unroll
    for (int m = 0; m < 4; ++m) {
        long gi0 = (long)m0 + wm * 64 + m * 16 + (lane >> 4) * 4;
#pragma unroll
        for (int n = 0; n < 4; ++n) {
            int col = nbz * 128 + wn * 64 + n * 16 + (lane & 15);
            if (z == 0) {
#pragma unroll
                for (int rg = 0; rg < 4; ++rg) {
                    long gi = gi0 + rg;
                    if (gi < M_) Kb[(size_t)gi * E + col] = f2bf(acc[m][n][rg]);
                }
            } else if (z == 2) {
                float bias = bq[col];
#pragma unroll
                for (int rg = 0; rg < 4; ++rg) {
                    long gi = gi0 + rg;
                    if (gi < M_)
                        Qo[(size_t)gi * E + col] = f2bf((acc[m][n][rg] + bias) * QSC);
                }
            } else {
                float bias = bv[col];
                if (gi0 + 3 < M_) {
                    long bb = gi0 / SEQ_, t0 = gi0 % SEQ_;
                    union { unsigned int u[2]; ushort4v v; } pk;
                    pk.u[0] = cvt_pk_bf16(acc[m][n][0] + bias, acc[m][n][1] + bias);
                    pk.u[1] = cvt_pk_bf16(acc[m][n][2] + bias, acc[m][n][3] + bias);
                    *(ushort4v*)(Vt + ((size_t)bb * E + col) * SEQ_ + t0) = pk.v;
                } else {
#pragma unroll
                    for (int rg = 0; rg < 4; ++rg) {
                        long gi = gi0 + rg;
                        if (gi < M_) {
                            long bb = gi / SEQ_, t = gi % SEQ_;
                            Vt[((size_t)bb * E + col) * SEQ_ + t] =
                                f2bf(acc[m][n][rg] + bias);
                        }
                    }
                }
            }
        }
    }
}

__global__ __launch_bounds__(256, 2) void oproj_kernel(
    const unsigned short* __restrict__ Ab, const float* __restrict__ Wo,
    const float* __restrict__ bo, float* __restrict__ out)
{
    __shared__ unsigned short As[128 * 64], Bs[128 * 64];
    const int sid = blockIdx.x, cpx = gridDim.x >> 3;
    const int nid = (sid & 7) * cpx + (sid >> 3);
    const int mb = nid >> 3, nb = nid & 7;
    const size_t m0 = (size_t)mb * 128;
    const int avalid = (M_ - (int)m0) < 128 ? (M_ - (int)m0) : 128;

    f32x4 acc[4][4];
#pragma unroll
    for (int m = 0; m < 4; ++m)
#pragma unroll
        for (int n = 0; n < 4; ++n)
#pragma unroll
            for (int i = 0; i < 4; ++i) acc[m][n][i] = 0.f;

    gemm128<true>(nullptr, Ab, m0, avalid, Wo, nb * 128, As, Bs, threadIdx.x, acc);

    const int tid = threadIdx.x, lane = tid & 63;
    const int wm = (tid >> 7), wn = (tid >> 6) & 1;
#pragma unroll
    for (int m = 0; m < 4; ++m) {
        long gi0 = (long)m0 + wm * 64 + m * 16 + (lane >> 4) * 4;
#pragma unroll
        for (int n = 0; n < 4; ++n) {
            int col = nb * 128 + wn * 64 + n * 16 + (lane & 15);
            float bias = bo[col];
#pragma unroll
            for (int rg = 0; rg < 4; ++rg) {
                long gi = gi0 + rg;
                if (gi < M_) out[(size_t)gi * E + col] = acc[m][n][rg] + bias;
            }
        }
    }
}

// ===========================================================================
// Attention r11: in-block K-split. 512 threads = 2 groups x 4 warps.
// Group kh handles keys [kh*768, kh*768+750ish); warp wz&3 owns 32 q-rows.
// Unnormalized fp32 partials combined through LDS (no HBM partials).
// Core tile math identical to r9 (proven on HW).
// ===========================================================================
__global__ __launch_bounds__(512, 4) void attn_kernel2(
    const unsigned short* __restrict__ Kb,
    const unsigned short* __restrict__ Vt,
    unsigned short* __restrict__ Qa)
{
    // tiles: [ks_h0 | ks_h1 | vs_h0 | vs_h1], each 4096 ushorts (8KB) = 32KB.
    __shared__ unsigned short tiles[16384];
    __shared__ float lsumb[128];
    const int sid = blockIdx.x;
    const int nid = (sid & 7) * 96 + (sid >> 3);   // 768 blocks, 96/XCD
    const int bh = nid / 12, qb = nid % 12;
    const int b = bh >> 4, hh = bh & 15;
    const int tid = threadIdx.x;
    const int kh = tid >> 8;               // key-half group
    const int gtid = tid & 255;            // tid within group
    const int lane = tid & 63, wz = (tid >> 6) & 3;
    const int c = lane & 31, g2 = lane >> 5;
    const int q0 = qb * 128 + wz * 32;

    unsigned short* ks = tiles + kh * 4096;
    unsigned short* vs = tiles + 8192 + kh * 4096;

    const unsigned short* kbase = Kb + (size_t)b * SEQ_ * E + hh * 64;
    const unsigned short* vbase = Vt + ((size_t)b * E + hh * 64) * SEQ_;

    short8v kreg[2];
    ushort4v vreg[4];
    auto loadK = [&](int kt0) {
#pragma unroll
        for (int uu = 0; uu < 2; ++uu) {
            int u = gtid + uu * 256, key = u >> 3, slot = (u & 7) * 8;
            short8v t;
#pragma unroll
            for (int i = 0; i < 8; ++i) t[i] = 0;
            int gk = kt0 + key;
            if (gk < SEQ_) t = *(const short8v*)(kbase + (size_t)gk * E + slot);
            kreg[uu] = t;
        }
    };
    auto loadV = [&](int kt0) {
#pragma unroll
        for (int uu = 0; uu < 4; ++uu) {
            int u = gtid + uu * 256, d = u >> 4, q4 = (u & 15) * 4;
            ushort4v t; t[0] = t[1] = t[2] = t[3] = 0;
            int col = kt0 + q4, rem = SEQ_ - col;
            const unsigned short* src = vbase + (size_t)d * SEQ_ + col;
            if (rem >= 4) t = *(const ushort4v*)src;
            else if (rem > 0) { for (int e2 = 0; e2 < 4; ++e2) if (e2 < rem) t[e2] = src[e2]; }
            vreg[uu] = t;
        }
    };
    auto commitKV = [&]() {
#pragma unroll
        for (int uu = 0; uu < 2; ++uu) {
            int u = gtid + uu * 256;
            *(short8v*)(ks + swzf(u >> 3, (u & 7) * 8)) = kreg[uu];
        }
#pragma unroll
        for (int uu = 0; uu < 4; ++uu) {
            int u = gtid + uu * 256;
            *(ushort4v*)(vs + swzf(u >> 4, (u & 15) * 4)) = vreg[uu];
        }
    };

    const int kbeg = kh * 768;             // group's key base
    loadK(kbeg); loadV(kbeg);

    // Q B-frags in registers: qf[t] holds q=q0+c, d = t*16 + 8*g2 + 0..7
    short8v qf[4];
    {
        int qr = q0 + c;
        bool ok = qr < SEQ_;
        const unsigned short* qp = Qa + ((size_t)b * SEQ_ + qr) * E + hh * 64 + 8 * g2;
#pragma unroll
        for (int t = 0; t < 4; ++t) {
            short8v zv;
#pragma unroll
            for (int i = 0; i < 8; ++i) zv[i] = 0;
            if (ok) zv = *(const short8v*)(qp + t * 16);
            qf[t] = zv;
        }
    }

    f32x16 o0, o1;
#pragma unroll
    for (int i = 0; i < 16; ++i) { o0[i] = 0.f; o1[i] = 0.f; }
    float lsum = 0.f;

    for (int it = 0; it < 12; ++it) {
        const int kt0 = kbeg + it * 64;
        __syncthreads();            // prev tile's frag reads done
        commitKV();
        __syncthreads();            // tile ready
        if (it + 1 < 12) { loadK(kt0 + 64); loadV(kt0 + 64); }  // overlap
        const bool tail = (kt0 + 64 > SEQ_);

#pragma unroll
        for (int nt = 0; nt < 2; ++nt) {
            // S^T = mfma(K, Q): lane holds q=c, keys=(reg&3)+8*(reg>>2)+4*g2
            f32x16 s;
#pragma unroll
            for (int i = 0; i < 16; ++i) s[i] = 0.f;
            __builtin_amdgcn_s_setprio(1);
#pragma unroll
            for (int t = 0; t < 4; ++t) {
                short8v af = *(const short8v*)(ks + swzf(nt * 32 + c, t * 16 + 8 * g2));
                s = __builtin_amdgcn_mfma_f32_32x32x16_bf16(af, qf[t], s, 0, 0, 0);
            }
            __builtin_amdgcn_s_setprio(0);
            if (tail) {
#pragma unroll
                for (int r = 0; r < 16; ++r) {
                    int key = kt0 + nt * 32 + (r & 3) + 8 * (r >> 2) + 4 * g2;
                    if (key >= SEQ_) s[r] = -1e30f;   // exp2 -> 0
                }
            }
            // max-free softmax fused with pack (scores |s|~O(3))
            unsigned int pk[8];
            float ls0 = 0.f, ls1 = 0.f;
#pragma unroll
            for (int h = 0; h < 8; ++h) {
                float p0 = __builtin_amdgcn_exp2f(s[2 * h]);
                float p1 = __builtin_amdgcn_exp2f(s[2 * h + 1]);
                if (h & 1) ls1 += p0 + p1; else ls0 += p0 + p1;
                pk[h] = cvt_pk_bf16(p0, p1);
            }
            lsum += ls0 + ls1;
            perml32(pk[0], pk[2]); perml32(pk[1], pk[3]);
            perml32(pk[4], pk[6]); perml32(pk[5], pk[7]);
            // PV
            __builtin_amdgcn_s_setprio(1);
#pragma unroll
            for (int tau = 0; tau < 2; ++tau) {
                union { unsigned int w[4]; short8v v; } pa;
                pa.w[0] = pk[4 * tau + 0];
                pa.w[1] = pk[4 * tau + 1];
                pa.w[2] = pk[4 * tau + 2];
                pa.w[3] = pk[4 * tau + 3];
                int t = nt * 2 + tau;
                short8v vb0 = *(const short8v*)(vs + swzf(0 + c, t * 16 + 8 * g2));
                short8v vb1 = *(const short8v*)(vs + swzf(32 + c, t * 16 + 8 * g2));
                o0 = __builtin_amdgcn_mfma_f32_32x32x16_bf16(pa.v, vb0, o0, 0, 0, 0);
                o1 = __builtin_amdgcn_mfma_f32_32x32x16_bf16(pa.v, vb1, o1, 0, 0, 0);
            }
            __builtin_amdgcn_s_setprio(0);
        }
    }

    // ---- in-LDS combine of the two key-halves ----
    lsum += __shfl_xor(lsum, 32, 64);      // lane now has half-sum for q=c
    __syncthreads();                       // all tile reads done; reuse tiles
    float* comb = (float*)tiles;           // 8192 floats = 32KB
    float* cw = comb + wz * 2048;          // warp-pair slot: 32 rows x 64 cols
    if (kh == 1) {
#pragma unroll
        for (int r = 0; r < 16; ++r) {
            int ql = (r & 3) + 8 * (r >> 2) + 4 * g2;
            cw[ql * 64 + c] = o0[r];
            cw[ql * 64 + 32 + c] = o1[r];
        }
        if (lane < 32) lsumb[wz * 32 + c] = lsum;
    }
    __syncthreads();
    if (kh == 0) {
        float* lf = lsumb + wz * 32;
        if (lane < 32) lf[c] = 1.0f / (lsum + lf[c]);
        // same-wave LDS write->read; lgkmcnt orders it (r9-proven pattern)
#pragma unroll
        for (int r = 0; r < 16; ++r) {
            int ql = (r & 3) + 8 * (r >> 2) + 4 * g2;
            int tq = q0 + ql;
            if (tq < SEQ_) {
                float inv = lf[ql];
                unsigned short* op = Qa + ((size_t)b * SEQ_ + tq) * E + hh * 64;
                op[c] = f2bf((o0[r] + cw[ql * 64 + c]) * inv);
                op[32 + c] = f2bf((o1[r] + cw[ql * 64 + 32 + c]) * inv);
            }
        }
    }
}

extern "C" void kernel_launch(void* const* d_in, const int* in_sizes, int n_in,
                              void* d_out, int out_size, void* d_ws, size_t ws_size,
                              hipStream_t stream) {
    const float* hs = (const float*)d_in[0];
    const float* Wq = (const float*)d_in[1];
    const float* bq = (const float*)d_in[2];
    const float* Wk = (const float*)d_in[3];
    const float* Wv = (const float*)d_in[4];
    const float* bv = (const float*)d_in[5];
    const float* Wo = (const float*)d_in[6];
    const float* bo = (const float*)d_in[7];

    // d_out hosts K bf16 [6000][1024] | V^T bf16 [4][1024][1500] (fully
    // rewritten by oproj at the end). ws: Qa bf16 + bf16 operand cache.
    // Attn overwrites Qa in place with its output.
    unsigned short* Kb = (unsigned short*)d_out;
    unsigned short* Vt = (unsigned short*)d_out + SZE;
    unsigned short* ws = (unsigned short*)d_ws;
    unsigned short* Qa = ws + QA_OFF;
    float* out = (float*)d_out;

    if (ws_size >= WS_NEED_BYTES) {
        cvt_kernel<<<dim3(5048), 256, 0, stream>>>(hs, Wk, Wv, Wq, Wo, ws);
        proj_fast<<<dim3(1128), 256, 0, stream>>>(ws + XB_OFF, ws + WB_OFF,
                                                  bv, bq, Kb, Vt, Qa);
        attn_kernel2<<<dim3(768), 512, 0, stream>>>(Kb, Vt, Qa);
        oproj_fast<<<dim3(376), 256, 0, stream>>>(Qa, ws + WOB_OFF, bo, out);
    } else {
        proj_kernel<<<dim3(47 * 24), 256, 0, stream>>>(hs, Wk, Wv, bv, Wq, bq,
                                                       Kb, Vt, Qa);
        attn_kernel2<<<dim3(768), 512, 0, stream>>>(Kb, Vt, Qa);
        oproj_kernel<<<dim3(47 * 8), 256, 0, stream>>>(Qa, Wo, bo, out);
    }
}

// Round 13
// 160.371 us; speedup vs baseline: 1.9651x; 1.2210x over previous
//
#include <hip/hip_runtime.h>
#include <math.h>

#define E 1024
#define NH 16
#define HD 64
#define BSZ_ 4
#define SEQ_ 1500
#define VSTR 1504                        // padded V^T row stride (16B-aligned)
#define M_ (BSZ_ * SEQ_)                 // 6000
#define SZE ((size_t)M_ * (size_t)E)     // 6,144,000
#define QSC (0.125f * 1.44269504f)       // fold log2e: P = exp2(s)

// ws layout (ushort offsets), fast path:
#define QA_OFF  0u                        // Q / attn-out bf16 [6000][1024]
#define XB_OFF  6144000u                  // X bf16 [6000][1024]
#define WB_OFF  12288000u                 // [Wk;Wv;Wq*QSC] bf16 [3072][1024]
#define WOB_OFF 15433728u                 // Wo bf16 [1024][1024]
#define VT_OFF  16482304u                 // V^T bf16 [4][1024][VSTR] + 2048 pad
#define CVT_TOTAL 10338304u               // elems converted by cvt
#define PAD_ELEMS 18432u                  // 4096*4 row-pad + 2048 tail-pad
#define WS_FAST_BYTES 45289472ull         // (VT_OFF + 4096*VSTR + 2048)*2

typedef __attribute__((ext_vector_type(8))) short short8v;    // 8 bf16
typedef __attribute__((ext_vector_type(4))) float f32x4;
typedef __attribute__((ext_vector_type(16))) float f32x16;
typedef __attribute__((ext_vector_type(4))) unsigned short ushort4v;

__device__ __forceinline__ unsigned short f2bf(float f) {
    union { float f; unsigned int i; } c; c.f = f;
    return (unsigned short)((c.i + 0x7FFFu + ((c.i >> 16) & 1u)) >> 16);
}
__device__ __forceinline__ unsigned int cvt_pk_bf16(float a, float b) {
    unsigned int r;
    asm("v_cvt_pk_bf16_f32 %0, %1, %2" : "=v"(r) : "v"(a), "v"(b));
    return r;
}
// v_permlane32_swap_b32: a'[l] = l<32 ? a[l] : b[l-32]; b'[l] = l<32 ? a[l+32] : b[l]
__device__ __forceinline__ void perml32(unsigned int &a, unsigned int &b) {
    asm("v_permlane32_swap_b32 %0, %1" : "+v"(a), "+v"(b));
}

// Swizzled short-index into [R][64] bf16 LDS tiles (proven r4-r9).
__device__ __forceinline__ int swz(int row, int col) {
    return (row << 6) + ((((col >> 3) ^ row) & 7) << 3) + (col & 7);
}
// Folded swizzle for attn K/V tiles (proven r6-r9).
__device__ __forceinline__ int swzf(int r, int d) {
    int row = r >> 1;
    int cs = ((r & 1) << 3) | (d >> 3);
    return row * 128 + ((cs ^ (row & 15)) << 3) + (d & 7);
}

__device__ __forceinline__ short8v pack8(const float* x) {
    union { unsigned int u[4]; short8v v; } r;
    r.u[0] = cvt_pk_bf16(x[0], x[1]);
    r.u[1] = cvt_pk_bf16(x[2], x[3]);
    r.u[2] = cvt_pk_bf16(x[4], x[5]);
    r.u[3] = cvt_pk_bf16(x[6], x[7]);
    return r.v;
}

// async global->LDS, 16B per lane; LDS dest wave-uniform base + lane*16.
__device__ __forceinline__ void gload16(const unsigned short* g,
                                        unsigned short* l) {
    __builtin_amdgcn_global_load_lds(
        (const __attribute__((address_space(1))) unsigned int*)(g),
        (__attribute__((address_space(3))) unsigned int*)(l), 16, 0, 0);
}

// ===========================================================================
// fp32 -> bf16 conversion of X, Wk, Wv, Wq(*QSC), Wo into ws; zero V pads.
// ===========================================================================
__global__ __launch_bounds__(256) void cvt_kernel(
    const float* __restrict__ X,  const float* __restrict__ Wk,
    const float* __restrict__ Wv, const float* __restrict__ Wq,
    const float* __restrict__ Wo, unsigned short* __restrict__ ws)
{
    size_t w = ((size_t)blockIdx.x * 256 + threadIdx.x) * 8;
    if (w >= CVT_TOTAL) {                 // pad-zero job (NaN-safety for PV)
        size_t p0 = w - CVT_TOTAL;
        unsigned short* Vt = ws + VT_OFF;
#pragma unroll
        for (int i = 0; i < 8; ++i) {
            size_t e = p0 + i;
            if (e < 16384u) {             // row pads: cols 1500..1503, 4096 rows
                size_t row = e >> 2;
                Vt[row * VSTR + 1500 + (e & 3)] = 0;
            } else if (e < PAD_ELEMS) {   // tail pad
                Vt[(size_t)4096 * VSTR + (e - 16384u)] = 0;
            }
        }
        return;
    }
    const float* s; unsigned short* d; float sc = 1.0f;
    if (w < 6144000u)      { s = X  + w;             d = ws + XB_OFF + w; }
    else if (w < 7192576u) { s = Wk + (w - 6144000u); d = ws + WB_OFF + (w - 6144000u); }
    else if (w < 8241152u) { s = Wv + (w - 7192576u); d = ws + WB_OFF + 1048576u + (w - 7192576u); }
    else if (w < 9289728u) { s = Wq + (w - 8241152u); d = ws + WB_OFF + 2097152u + (w - 8241152u); sc = QSC; }
    else                   { s = Wo + (w - 9289728u); d = ws + WOB_OFF + (w - 9289728u); }
    float t[8];
    *(float4*)t = *(const float4*)s;
    *(float4*)(t + 4) = *(const float4*)(s + 4);
#pragma unroll
    for (int i = 0; i < 8; ++i) t[i] *= sc;
    *(short8v*)d = pack8(t);
}

// ---------------------------------------------------------------------------
// m97-structure 128x128x1024 GEMM body (proven r8): single-buffer LDS,
// global_load_lds with pre-swizzled global source, 2 barriers/step.
// ---------------------------------------------------------------------------
__device__ __forceinline__ void gemm128b(
    const unsigned short* __restrict__ Arow,
    const unsigned short* __restrict__ Brow,
    unsigned short* As, unsigned short* Bs, int tid, f32x4 acc[4][4])
{
    const int lane = tid & 63, wid = tid >> 6;
    const int wm = tid >> 7, wn = (tid >> 6) & 1;
    for (int k0 = 0; k0 < E; k0 += 64) {
#pragma unroll
        for (int i = 0; i < 4; ++i) {
            int row = wid * 32 + i * 8 + (lane >> 3);
            int sl = (lane & 7) ^ (row & 7);            // inverse-swz source
            unsigned short* lbase = As + (wid * 32 + i * 8) * 64;
            gload16(Arow + (size_t)row * E + k0 + sl * 8, lbase);
            unsigned short* lbase2 = Bs + (wid * 32 + i * 8) * 64;
            gload16(Brow + (size_t)row * E + k0 + sl * 8, lbase2);
        }
        __syncthreads();          // vmcnt(0) drain: tiles ready
#pragma unroll
        for (int kk = 0; kk < 64; kk += 32) {
            short8v afr[4], bfr[4];
#pragma unroll
            for (int m = 0; m < 4; ++m)
                afr[m] = *(const short8v*)(As + swz(wm * 64 + m * 16 + (lane & 15),
                                                    kk + (lane >> 4) * 8));
#pragma unroll
            for (int n = 0; n < 4; ++n)
                bfr[n] = *(const short8v*)(Bs + swz(wn * 64 + n * 16 + (lane & 15),
                                                    kk + (lane >> 4) * 8));
            __builtin_amdgcn_s_setprio(1);
#pragma unroll
            for (int m = 0; m < 4; ++m)
#pragma unroll
                for (int n = 0; n < 4; ++n)
                    acc[m][n] = __builtin_amdgcn_mfma_f32_16x16x32_bf16(
                        afr[m], bfr[n], acc[m][n], 0, 0, 0);
            __builtin_amdgcn_s_setprio(0);
        }
        __syncthreads();          // frag reads done before next stage
    }
}

// Projections (fast): nb 0-7: K; 8-15: V(+bv, ->V^T stride VSTR); 16-23: Q.
__global__ __launch_bounds__(256) void proj_fast(
    const unsigned short* __restrict__ Xb, const unsigned short* __restrict__ Wb,
    const float* __restrict__ bv, const float* __restrict__ bq,
    unsigned short* __restrict__ Kb, unsigned short* __restrict__ Vt,
    unsigned short* __restrict__ Qa)
{
    __shared__ unsigned short As[128 * 64], Bs[128 * 64];
    const int sid = blockIdx.x;
    const int nid = (sid & 7) * 141 + (sid >> 3);        // T1 XCD-chunked
    const int mb = nid / 24, nb = nid % 24;
    const int z = nb >> 3;
    const size_t m0 = (size_t)mb * 128;
    const int tid = threadIdx.x, lane = tid & 63;
    const int wm = tid >> 7, wn = (tid >> 6) & 1;

    f32x4 acc[4][4];
#pragma unroll
    for (int m = 0; m < 4; ++m)
#pragma unroll
        for (int n = 0; n < 4; ++n)
#pragma unroll
            for (int i = 0; i < 4; ++i) acc[m][n][i] = 0.f;

    gemm128b(Xb + m0 * E, Wb + (size_t)nb * 128 * E, As, Bs, tid, acc);

#pragma unroll
    for (int m = 0; m < 4; ++m) {
        long gi0 = (long)m0 + wm * 64 + m * 16 + (lane >> 4) * 4;
#pragma unroll
        for (int n = 0; n < 4; ++n) {
            int col = (nb & 7) * 128 + wn * 64 + n * 16 + (lane & 15);
            if (z == 0) {
#pragma unroll
                for (int rg = 0; rg < 4; ++rg) {
                    long gi = gi0 + rg;
                    if (gi < M_) Kb[(size_t)gi * E + col] = f2bf(acc[m][n][rg]);
                }
            } else if (z == 2) {
                float bias = bq[col] * QSC;
#pragma unroll
                for (int rg = 0; rg < 4; ++rg) {
                    long gi = gi0 + rg;
                    if (gi < M_)
                        Qa[(size_t)gi * E + col] = f2bf(acc[m][n][rg] + bias);
                }
            } else {
                float bias = bv[col];
                if (gi0 + 3 < M_) {      // quad never crosses batch (SEQ_%4==0)
                    long bb = gi0 / SEQ_, t0 = gi0 % SEQ_;
                    union { unsigned int u[2]; ushort4v v; } pk;
                    pk.u[0] = cvt_pk_bf16(acc[m][n][0] + bias, acc[m][n][1] + bias);
                    pk.u[1] = cvt_pk_bf16(acc[m][n][2] + bias, acc[m][n][3] + bias);
                    *(ushort4v*)(Vt + ((size_t)bb * E + col) * VSTR + t0) = pk.v;
                } else {
#pragma unroll
                    for (int rg = 0; rg < 4; ++rg) {
                        long gi = gi0 + rg;
                        if (gi < M_) {
                            long bb = gi / SEQ_, t = gi % SEQ_;
                            Vt[((size_t)bb * E + col) * VSTR + t] =
                                f2bf(acc[m][n][rg] + bias);
                        }
                    }
                }
            }
        }
    }
}

// Output projection (fast): A = attn-out bf16 (Qa region), B = Wob bf16.
__global__ __launch_bounds__(256) void oproj_fast(
    const unsigned short* __restrict__ Ab, const unsigned short* __restrict__ Wob,
    const float* __restrict__ bo, float* __restrict__ out)
{
    __shared__ unsigned short As[128 * 64], Bs[128 * 64];
    const int sid = blockIdx.x;
    const int nid = (sid & 7) * 47 + (sid >> 3);         // 376 blocks
    const int mb = nid >> 3, nb = nid & 7;
    const size_t m0 = (size_t)mb * 128;
    const int tid = threadIdx.x, lane = tid & 63;
    const int wm = tid >> 7, wn = (tid >> 6) & 1;

    f32x4 acc[4][4];
#pragma unroll
    for (int m = 0; m < 4; ++m)
#pragma unroll
        for (int n = 0; n < 4; ++n)
#pragma unroll
            for (int i = 0; i < 4; ++i) acc[m][n][i] = 0.f;

    gemm128b(Ab + m0 * E, Wob + (size_t)nb * 128 * E, As, Bs, tid, acc);

#pragma unroll
    for (int m = 0; m < 4; ++m) {
        long gi0 = (long)m0 + wm * 64 + m * 16 + (lane >> 4) * 4;
#pragma unroll
        for (int n = 0; n < 4; ++n) {
            int col = nb * 128 + wn * 64 + n * 16 + (lane & 15);
            float bias = bo[col];
#pragma unroll
            for (int rg = 0; rg < 4; ++rg) {
                long gi = gi0 + rg;
                if (gi < M_) out[(size_t)gi * E + col] = acc[m][n][rg] + bias;
            }
        }
    }
}

// ===========================================================================
// Attention r13: r8's proven structure + global_load_lds staging with
// pre-swizzled global source (inverse of swzf, verified vs gemm128b pattern).
// Single-buffer, 2 barriers/tile. V^T rows stride VSTR (16B-aligned), pad
// columns zeroed (NaN safety). Softmax/PV/epilogue byte-identical to r8.
// ===========================================================================
__global__ __launch_bounds__(256, 4) void attn_gl(
    const unsigned short* __restrict__ Kb,   // [6000][1024] bf16 (d_out)
    const unsigned short* __restrict__ Vt,   // [4][1024][VSTR] bf16 (ws)
    unsigned short* __restrict__ Qa)         // Q in, attn-out overwrites
{
    __shared__ unsigned short ks[4096], vs[4096];   // 8KB + 8KB
    const int sid = blockIdx.x;
    const int nid = (sid & 7) * 96 + (sid >> 3);    // 768 blocks, 96/XCD
    const int bh = nid / 12, qb = nid % 12;
    const int b = bh >> 4, hh = bh & 15;
    const int tid = threadIdx.x, lane = tid & 63, wz = tid >> 6;
    const int c = lane & 31, g2 = lane >> 5;
    const int q0 = qb * 128 + wz * 32;

    const unsigned short* kbase = Kb + (size_t)b * SEQ_ * E + hh * 64;
    const unsigned short* vbase = Vt + ((size_t)b * E + hh * 64) * VSTR;

    // Stage one 64-key tile of K and V via global_load_lds. 16B-chunk j of
    // the swzf layout holds element-block (r, s): rp=j>>4, u=(j&15)^(rp&15),
    // r=2rp+(u>>3), s=u&7. K chunk (r=key_rel, s=d-slot); V chunk (r=d,
    // s=key-slot). LDS dest is linear (wave-uniform base + lane*16).
    auto stageKV = [&](int kt0) {
#pragma unroll
        for (int i = 0; i < 2; ++i) {
            int j = (i * 4 + wz) * 64 + lane;
            int rp = j >> 4;
            int u = (j & 15) ^ (rp & 15);
            int r = rp * 2 + (u >> 3);
            int s = u & 7;
            gload16(kbase + (size_t)(kt0 + r) * E + s * 8,
                    ks + (i * 4 + wz) * 512);
            gload16(vbase + (size_t)r * VSTR + kt0 + s * 8,
                    vs + (i * 4 + wz) * 512);
        }
    };

    // Q B-frags in registers: qf[t] holds q=q0+c, d = t*16 + 8*g2 + 0..7
    short8v qf[4];
    {
        int qr = q0 + c;
        bool ok = qr < SEQ_;
        const unsigned short* qp = Qa + ((size_t)b * SEQ_ + qr) * E + hh * 64 + 8 * g2;
#pragma unroll
        for (int t = 0; t < 4; ++t) {
            short8v zv;
#pragma unroll
            for (int i = 0; i < 8; ++i) zv[i] = 0;
            if (ok) zv = *(const short8v*)(qp + t * 16);
            qf[t] = zv;
        }
    }

    f32x16 o0, o1;
#pragma unroll
    for (int i = 0; i < 16; ++i) { o0[i] = 0.f; o1[i] = 0.f; }
    float lsum = 0.f;

    const int NT = (SEQ_ + 63) / 64;     // 24
    for (int it = 0; it < NT; ++it) {
        const int kt0 = it * 64;
        __syncthreads();            // prev tile's frag reads done
        stageKV(kt0);
        __syncthreads();            // vmcnt(0) drain before barrier: tile ready
        const bool tail = (kt0 + 64 > SEQ_);

#pragma unroll
        for (int nt = 0; nt < 2; ++nt) {
            // S^T = mfma(K, Q): lane holds q=c, keys=(reg&3)+8*(reg>>2)+4*g2
            f32x16 s;
#pragma unroll
            for (int i = 0; i < 16; ++i) s[i] = 0.f;
            __builtin_amdgcn_s_setprio(1);
#pragma unroll
            for (int t = 0; t < 4; ++t) {
                short8v af = *(const short8v*)(ks + swzf(nt * 32 + c, t * 16 + 8 * g2));
                s = __builtin_amdgcn_mfma_f32_32x32x16_bf16(af, qf[t], s, 0, 0, 0);
            }
            __builtin_amdgcn_s_setprio(0);
            if (tail) {
#pragma unroll
                for (int r = 0; r < 16; ++r) {
                    int key = kt0 + nt * 32 + (r & 3) + 8 * (r >> 2) + 4 * g2;
                    if (key >= SEQ_) s[r] = -1e30f;   // exp2 -> 0 (assignment)
                }
            }
            // max-free softmax fused with pack (scores |s|~O(3))
            unsigned int pk[8];
            float ls0 = 0.f, ls1 = 0.f;
#pragma unroll
            for (int h = 0; h < 8; ++h) {
                float p0 = __builtin_amdgcn_exp2f(s[2 * h]);
                float p1 = __builtin_amdgcn_exp2f(s[2 * h + 1]);
                if (h & 1) ls1 += p0 + p1; else ls0 += p0 + p1;
                pk[h] = cvt_pk_bf16(p0, p1);
            }
            lsum += ls0 + ls1;
            perml32(pk[0], pk[2]); perml32(pk[1], pk[3]);
            perml32(pk[4], pk[6]); perml32(pk[5], pk[7]);
            // PV
            __builtin_amdgcn_s_setprio(1);
#pragma unroll
            for (int tau = 0; tau < 2; ++tau) {
                union { unsigned int ww[4]; short8v v; } pa;
                pa.ww[0] = pk[4 * tau + 0];
                pa.ww[1] = pk[4 * tau + 1];
                pa.ww[2] = pk[4 * tau + 2];
                pa.ww[3] = pk[4 * tau + 3];
                int t = nt * 2 + tau;
                short8v vb0 = *(const short8v*)(vs + swzf(0 + c, t * 16 + 8 * g2));
                short8v vb1 = *(const short8v*)(vs + swzf(32 + c, t * 16 + 8 * g2));
                o0 = __builtin_amdgcn_mfma_f32_32x32x16_bf16(pa.v, vb0, o0, 0, 0, 0);
                o1 = __builtin_amdgcn_mfma_f32_32x32x16_bf16(pa.v, vb1, o1, 0, 0, 0);
            }
            __builtin_amdgcn_s_setprio(0);
        }
    }

    // epilogue (r8-proven): fold lsum halves, broadcast 1/lsum via LDS, store
    lsum += __shfl_xor(lsum, 32, 64);
    __syncthreads();
    float* lf = (float*)ks + wz * 32;
    if (lane < 32) lf[c] = 1.0f / lsum;
#pragma unroll
    for (int r = 0; r < 16; ++r) {
        int ql = (r & 3) + 8 * (r >> 2) + 4 * g2;
        int tq = q0 + ql;
        if (tq < SEQ_) {
            float inv = lf[ql];
            unsigned short* op = Qa + ((size_t)b * SEQ_ + tq) * E + hh * 64;
            op[c] = f2bf(o0[r] * inv);
            op[32 + c] = f2bf(o1[r] * inv);
        }
    }
}

// ===========================================================================
// FALLBACK PATH (ws too small; not expected - r10 proved ws >= 83MB).
// r7 fp32-reg-staged GEMM + r9 LDS-staged attention, K|Vt(1500) in d_out.
// ===========================================================================
template <bool ABF>
__device__ __forceinline__ void gemm128(
    const float* __restrict__ Af, const unsigned short* __restrict__ Ab,
    size_t arow0, int avalid,
    const float* __restrict__ W, int wrow0,
    unsigned short* As, unsigned short* Bs,
    int tid, f32x4 acc[4][4])
{
    const int lane = tid & 63;
    const int wm = (tid >> 7), wn = (tid >> 6) & 1;
    float4 pA[8]; short8v pAb[4]; float4 pB[8];

    auto loadT = [&](int k0) {
#pragma unroll
        for (int uu = 0; uu < 4; ++uu) {
            int u = tid + uu * 256, row = u >> 3, sl = (u & 7) * 8;
            if constexpr (ABF) {
                short8v t;
#pragma unroll
                for (int i = 0; i < 8; ++i) t[i] = 0;
                if (row < avalid)
                    t = *(const short8v*)(Ab + (arow0 + row) * E + k0 + sl);
                pAb[uu] = t;
            } else {
                float4 x0 = make_float4(0.f, 0.f, 0.f, 0.f), x1 = x0;
                if (row < avalid) {
                    const float* p = Af + (arow0 + row) * (size_t)E + k0 + sl;
                    x0 = *(const float4*)p; x1 = *(const float4*)(p + 4);
                }
                pA[2 * uu] = x0; pA[2 * uu + 1] = x1;
            }
            const float* q = W + (size_t)(wrow0 + row) * E + k0 + sl;
            pB[2 * uu] = *(const float4*)q;
            pB[2 * uu + 1] = *(const float4*)(q + 4);
        }
    };
    auto commitT = [&]() {
#pragma unroll
        for (int uu = 0; uu < 4; ++uu) {
            int u = tid + uu * 256, row = u >> 3, sl = (u & 7) * 8;
            if constexpr (ABF) {
                *(short8v*)(As + swz(row, sl)) = pAb[uu];
            } else {
                float t[8];
                *(float4*)t = pA[2 * uu]; *(float4*)(t + 4) = pA[2 * uu + 1];
                *(short8v*)(As + swz(row, sl)) = pack8(t);
            }
            float t2[8];
            *(float4*)t2 = pB[2 * uu]; *(float4*)(t2 + 4) = pB[2 * uu + 1];
            *(short8v*)(Bs + swz(row, sl)) = pack8(t2);
        }
    };

    loadT(0);
    for (int k0 = 0; k0 < E; k0 += 64) {
        __syncthreads();
        commitT();
        __syncthreads();
        if (k0 + 64 < E) loadT(k0 + 64);
#pragma unroll
        for (int kk = 0; kk < 64; kk += 32) {
            short8v afr[4], bfr[4];
#pragma unroll
            for (int m = 0; m < 4; ++m)
                afr[m] = *(const short8v*)(As + swz(wm * 64 + m * 16 + (lane & 15),
                                                    kk + (lane >> 4) * 8));
#pragma unroll
            for (int n = 0; n < 4; ++n)
                bfr[n] = *(const short8v*)(Bs + swz(wn * 64 + n * 16 + (lane & 15),
                                                    kk + (lane >> 4) * 8));
            __builtin_amdgcn_s_setprio(1);
#pragma unroll
            for (int m = 0; m < 4; ++m)
#pragma unroll
                for (int n = 0; n < 4; ++n)
                    acc[m][n] = __builtin_amdgcn_mfma_f32_16x16x32_bf16(
                        afr[m], bfr[n], acc[m][n], 0, 0, 0);
            __builtin_amdgcn_s_setprio(0);
        }
    }
}

__global__ __launch_bounds__(256, 2) void proj_kernel(
    const float* __restrict__ X, const float* __restrict__ Wk,
    const float* __restrict__ Wv, const float* __restrict__ bv,
    const float* __restrict__ Wq, const float* __restrict__ bq,
    unsigned short* __restrict__ Kb, unsigned short* __restrict__ Vt,
    unsigned short* __restrict__ Qo)
{
    __shared__ unsigned short As[128 * 64], Bs[128 * 64];
    const int sid = blockIdx.x, cpx = gridDim.x >> 3;
    const int nid = (sid & 7) * cpx + (sid >> 3);
    const int mb = nid / 24, nb = nid % 24;
    const int z = nb >> 3, nbz = nb & 7;
    const size_t m0 = (size_t)mb * 128;
    const int avalid = (M_ - (int)m0) < 128 ? (M_ - (int)m0) : 128;
    const float* W = (z == 0) ? Wk : (z == 1) ? Wv : Wq;

    f32x4 acc[4][4];
#pragma unroll
    for (int m = 0; m < 4; ++m)
#pragma unroll
        for (int n = 0; n < 4; ++n)
#pragma unroll
            for (int i = 0; i < 4; ++i) acc[m][n][i] = 0.f;

    gemm128<false>(X, nullptr, m0, avalid, W, nbz * 128, As, Bs, threadIdx.x, acc);

    const int tid = threadIdx.x, lane = tid & 63;
    const int wm = (tid >> 7), wn = (tid >> 6) & 1;
#pragma unroll
    for (int m = 0; m < 4; ++m) {
        long gi0 = (long)m0 + wm * 64 + m * 16 + (lane >> 4) * 4;
#pragma unroll
        for (int n = 0; n < 4; ++n) {
            int col = nbz * 128 + wn * 64 + n * 16 + (lane & 15);
            if (z == 0) {
#pragma unroll
                for (int rg = 0; rg < 4; ++rg) {
                    long gi = gi0 + rg;
                    if (gi < M_) Kb[(size_t)gi * E + col] = f2bf(acc[m][n][rg]);
                }
            } else if (z == 2) {
                float bias = bq[col];
#pragma unroll
                for (int rg = 0; rg < 4; ++rg) {
                    long gi = gi0 + rg;
                    if (gi < M_)
                        Qo[(size_t)gi * E + col] = f2bf((acc[m][n][rg] + bias) * QSC);
                }
            } else {
                float bias = bv[col];
                if (gi0 + 3 < M_) {
                    long bb = gi0 / SEQ_, t0 = gi0 % SEQ_;
                    union { unsigned int u[2]; ushort4v v; } pk;
                    pk.u[0] = cvt_pk_bf16(acc[m][n][0] + bias, acc[m][n][1] + bias);
                    pk.u[1] = cvt_pk_bf16(acc[m][n][2] + bias, acc[m][n][3] + bias);
                    *(ushort4v*)(Vt + ((size_t)bb * E + col) * SEQ_ + t0) = pk.v;
                } else {
#pragma unroll
                    for (int rg = 0; rg < 4; ++rg) {
                        long gi = gi0 + rg;
                        if (gi < M_) {
                            long bb = gi / SEQ_, t = gi % SEQ_;
                            Vt[((size_t)bb * E + col) * SEQ_ + t] =
                                f2bf(acc[m][n][rg] + bias);
                        }
                    }
                }
            }
        }
    }
}

__global__ __launch_bounds__(256, 2) void oproj_kernel(
    const unsigned short* __restrict__ Ab, const float* __restrict__ Wo,
    const float* __restrict__ bo, float* __restrict__ out)
{
    __shared__ unsigned short As[128 * 64], Bs[128 * 64];
    const int sid = blockIdx.x, cpx = gridDim.x >> 3;
    const int nid = (sid & 7) * cpx + (sid >> 3);
    const int mb = nid >> 3, nb = nid & 7;
    const size_t m0 = (size_t)mb * 128;
    const int avalid = (M_ - (int)m0) < 128 ? (M_ - (int)m0) : 128;

    f32x4 acc[4][4];
#pragma unroll
    for (int m = 0; m < 4; ++m)
#pragma unroll
        for (int n = 0; n < 4; ++n)
#pragma unroll
            for (int i = 0; i < 4; ++i) acc[m][n][i] = 0.f;

    gemm128<true>(nullptr, Ab, m0, avalid, Wo, nb * 128, As, Bs, threadIdx.x, acc);

    const int tid = threadIdx.x, lane = tid & 63;
    const int wm = (tid >> 7), wn = (tid >> 6) & 1;
#pragma unroll
    for (int m = 0; m < 4; ++m) {
        long gi0 = (long)m0 + wm * 64 + m * 16 + (lane >> 4) * 4;
#pragma unroll
        for (int n = 0; n < 4; ++n) {
            int col = nb * 128 + wn * 64 + n * 16 + (lane & 15);
            float bias = bo[col];
#pragma unroll
            for (int rg = 0; rg < 4; ++rg) {
                long gi = gi0 + rg;
                if (gi < M_) out[(size_t)gi * E + col] = acc[m][n][rg] + bias;
            }
        }
    }
}

__global__ __launch_bounds__(256, 4) void attn_fallback(
    const unsigned short* __restrict__ Kb,
    const unsigned short* __restrict__ Vt,
    unsigned short* __restrict__ Qa)
{
    __shared__ unsigned short ks[2][32 * 128], vs[2][32 * 128];
    const int sid = blockIdx.x;
    const int nid = (sid & 7) * 96 + (sid >> 3);
    const int bh = nid / 12, qb = nid % 12;
    const int b = bh >> 4, hh = bh & 15;
    const int tid = threadIdx.x, lane = tid & 63, wz = tid >> 6;
    const int c = lane & 31, g2 = lane >> 5;
    const int q0 = qb * 128 + wz * 32;

    const unsigned short* kbase = Kb + (size_t)b * SEQ_ * E + hh * 64;
    const unsigned short* vbase = Vt + ((size_t)b * E + hh * 64) * SEQ_;

    short8v kreg[2];
    ushort4v vreg[4];
    auto loadK = [&](int kt0) {
#pragma unroll
        for (int uu = 0; uu < 2; ++uu) {
            int u = tid + uu * 256, key = u >> 3, slot = (u & 7) * 8;
            short8v t;
#pragma unroll
            for (int i = 0; i < 8; ++i) t[i] = 0;
            int gk = kt0 + key;
            if (gk < SEQ_) t = *(const short8v*)(kbase + (size_t)gk * E + slot);
            kreg[uu] = t;
        }
    };
    auto loadV = [&](int kt0) {
#pragma unroll
        for (int uu = 0; uu < 4; ++uu) {
            int u = tid + uu * 256, d = u >> 4, q4 = (u & 15) * 4;
            ushort4v t; t[0] = t[1] = t[2] = t[3] = 0;
            int col = kt0 + q4, rem = SEQ_ - col;
            const unsigned short* src = vbase + (size_t)d * SEQ_ + col;
            if (rem >= 4) t = *(const ushort4v*)src;
            else if (rem > 0) { for (int e2 = 0; e2 < 4; ++e2) if (e2 < rem) t[e2] = src[e2]; }
            vreg[uu] = t;
        }
    };
    auto commitKV = [&](unsigned short* kd, unsigned short* vd) {
#pragma unroll
        for (int uu = 0; uu < 2; ++uu) {
            int u = tid + uu * 256;
            *(short8v*)(kd + swzf(u >> 3, (u & 7) * 8)) = kreg[uu];
        }
#pragma unroll
        for (int uu = 0; uu < 4; ++uu) {
            int u = tid + uu * 256;
            *(ushort4v*)(vd + swzf(u >> 4, (u & 15) * 4)) = vreg[uu];
        }
    };

    loadK(0); loadV(0);

    short8v qf[4];
    {
        int qr = q0 + c;
        bool ok = qr < SEQ_;
        const unsigned short* qp = Qa + ((size_t)b * SEQ_ + qr) * E + hh * 64 + 8 * g2;
#pragma unroll
        for (int t = 0; t < 4; ++t) {
            short8v zv;
#pragma unroll
            for (int i = 0; i < 8; ++i) zv[i] = 0;
            if (ok) zv = *(const short8v*)(qp + t * 16);
            qf[t] = zv;
        }
    }

    f32x16 o0, o1;
#pragma unroll
    for (int i = 0; i < 16; ++i) { o0[i] = 0.f; o1[i] = 0.f; }
    float lsum = 0.f;

    commitKV(ks[0], vs[0]);
    __syncthreads();
    loadK(64); loadV(64);

    const int NT = (SEQ_ + 63) / 64;     // 24
    for (int it = 0; it < NT; ++it) {
        const int kt0 = it * 64;
        const unsigned short* kcur = ks[it & 1];
        const unsigned short* vcur = vs[it & 1];
        const bool tail = (kt0 + 64 > SEQ_);

#pragma unroll
        for (int nt = 0; nt < 2; ++nt) {
            f32x16 s;
#pragma unroll
            for (int i = 0; i < 16; ++i) s[i] = 0.f;
#pragma unroll
            for (int t = 0; t < 4; ++t) {
                short8v af = *(const short8v*)(kcur + swzf(nt * 32 + c, t * 16 + 8 * g2));
                s = __builtin_amdgcn_mfma_f32_32x32x16_bf16(af, qf[t], s, 0, 0, 0);
            }
            if (tail) {
#pragma unroll
                for (int r = 0; r < 16; ++r) {
                    int key = kt0 + nt * 32 + (r & 3) + 8 * (r >> 2) + 4 * g2;
                    if (key >= SEQ_) s[r] = -1e30f;
                }
            }
            unsigned int pk[8];
            float ls0 = 0.f, ls1 = 0.f;
#pragma unroll
            for (int h = 0; h < 8; ++h) {
                float p0 = __builtin_amdgcn_exp2f(s[2 * h]);
                float p1 = __builtin_amdgcn_exp2f(s[2 * h + 1]);
                if (h & 1) ls1 += p0 + p1; else ls0 += p0 + p1;
                pk[h] = cvt_pk_bf16(p0, p1);
            }
            lsum += ls0 + ls1;
            perml32(pk[0], pk[2]); perml32(pk[1], pk[3]);
            perml32(pk[4], pk[6]); perml32(pk[5], pk[7]);
#pragma unroll
            for (int tau = 0; tau < 2; ++tau) {
                union { unsigned int ww[4]; short8v v; } pa;
                pa.ww[0] = pk[4 * tau + 0];
                pa.ww[1] = pk[4 * tau + 1];
                pa.ww[2] = pk[4 * tau + 2];
                pa.ww[3] = pk[4 * tau + 3];
                int t = nt * 2 + tau;
                short8v vb0 = *(const short8v*)(vcur + swzf(0 + c, t * 16 + 8 * g2));
                short8v vb1 = *(const short8v*)(vcur + swzf(32 + c, t * 16 + 8 * g2));
                o0 = __builtin_amdgcn_mfma_f32_32x32x16_bf16(pa.v, vb0, o0, 0, 0, 0);
                o1 = __builtin_amdgcn_mfma_f32_32x32x16_bf16(pa.v, vb1, o1, 0, 0, 0);
            }
        }

        if (it + 1 < NT) {
            commitKV(ks[(it + 1) & 1], vs[(it + 1) & 1]);
            __syncthreads();
            if (it + 2 < NT) { loadK(kt0 + 128); loadV(kt0 + 128); }
        }
    }

    lsum += __shfl_xor(lsum, 32, 64);
    __syncthreads();
    float* lf = (float*)ks[0] + wz * 32;
    if (lane < 32) lf[c] = 1.0f / lsum;
#pragma unroll
    for (int r = 0; r < 16; ++r) {
        int ql = (r & 3) + 8 * (r >> 2) + 4 * g2;
        int tq = q0 + ql;
        if (tq < SEQ_) {
            float inv = lf[ql];
            unsigned short* op = Qa + ((size_t)b * SEQ_ + tq) * E + hh * 64;
            op[c] = f2bf(o0[r] * inv);
            op[32 + c] = f2bf(o1[r] * inv);
        }
    }
}

extern "C" void kernel_launch(void* const* d_in, const int* in_sizes, int n_in,
                              void* d_out, int out_size, void* d_ws, size_t ws_size,
                              hipStream_t stream) {
    const float* hs = (const float*)d_in[0];
    const float* Wq = (const float*)d_in[1];
    const float* bq = (const float*)d_in[2];
    const float* Wk = (const float*)d_in[3];
    const float* Wv = (const float*)d_in[4];
    const float* bv = (const float*)d_in[5];
    const float* Wo = (const float*)d_in[6];
    const float* bo = (const float*)d_in[7];

    unsigned short* Kb = (unsigned short*)d_out;     // K bf16, overwritten by oproj
    unsigned short* ws = (unsigned short*)d_ws;
    unsigned short* Qa = ws + QA_OFF;
    float* out = (float*)d_out;

    if (ws_size >= WS_FAST_BYTES) {
        unsigned short* Vt = ws + VT_OFF;            // padded V^T in ws
        cvt_kernel<<<dim3(5057), 256, 0, stream>>>(hs, Wk, Wv, Wq, Wo, ws);
        proj_fast<<<dim3(1128), 256, 0, stream>>>(ws + XB_OFF, ws + WB_OFF,
                                                  bv, bq, Kb, Vt, Qa);
        attn_gl<<<dim3(768), 256, 0, stream>>>(Kb, Vt, Qa);
        oproj_fast<<<dim3(376), 256, 0, stream>>>(Qa, ws + WOB_OFF, bo, out);
    } else {
        // fallback: r7 proj + r9 attn, K|Vt(stride 1500) in d_out
        unsigned short* Vt = (unsigned short*)d_out + SZE;
        proj_kernel<<<dim3(47 * 24), 256, 0, stream>>>(hs, Wk, Wv, bv, Wq, bq,
                                                       Kb, Vt, Qa);
        attn_fallback<<<dim3(768), 256, 0, stream>>>(Kb, Vt, Qa);
        oproj_kernel<<<dim3(47 * 8), 256, 0, stream>>>(Qa, Wo, bo, out);
    }
}

// Round 14
// 146.244 us; speedup vs baseline: 2.1549x; 1.0966x over previous
//
#include <hip/hip_runtime.h>
#include <math.h>

#define E 1024
#define NH 16
#define HD 64
#define BSZ_ 4
#define SEQ_ 1500
#define VSTR 1504                        // padded V^T row stride (16B-aligned)
#define M_ (BSZ_ * SEQ_)                 // 6000
#define SZE ((size_t)M_ * (size_t)E)     // 6,144,000
#define QSC (0.125f * 1.44269504f)       // fold log2e: P = exp2(s)

// ws layout (ushort offsets), fast path:
#define QA_OFF  0u                        // Q / attn-out bf16 [6000][1024]
#define XB_OFF  6144000u                  // X bf16 [6000][1024]
#define WB_OFF  12288000u                 // [Wk;Wv;Wq*QSC] bf16 [3072][1024]
#define WOB_OFF 15433728u                 // Wo bf16 [1024][1024]
#define VT_OFF  16482304u                 // V^T bf16 [4][1024][VSTR] + 2048 pad
#define CVT_TOTAL 10338304u               // elems converted by cvt
#define PAD_ELEMS 18432u                  // 4096*4 row-pad + 2048 tail-pad
#define WS_FAST_BYTES 45289472ull         // (VT_OFF + 4096*VSTR + 2048)*2

typedef __attribute__((ext_vector_type(8))) short short8v;    // 8 bf16
typedef __attribute__((ext_vector_type(4))) float f32x4;
typedef __attribute__((ext_vector_type(16))) float f32x16;
typedef __attribute__((ext_vector_type(4))) unsigned short ushort4v;

__device__ __forceinline__ unsigned short f2bf(float f) {
    union { float f; unsigned int i; } c; c.f = f;
    return (unsigned short)((c.i + 0x7FFFu + ((c.i >> 16) & 1u)) >> 16);
}
__device__ __forceinline__ unsigned int cvt_pk_bf16(float a, float b) {
    unsigned int r;
    asm("v_cvt_pk_bf16_f32 %0, %1, %2" : "=v"(r) : "v"(a), "v"(b));
    return r;
}
// v_permlane32_swap_b32: a'[l] = l<32 ? a[l] : b[l-32]; b'[l] = l<32 ? a[l+32] : b[l]
__device__ __forceinline__ void perml32(unsigned int &a, unsigned int &b) {
    asm("v_permlane32_swap_b32 %0, %1" : "+v"(a), "+v"(b));
}

// Swizzled index into [R][64] bf16 LDS tiles (fallback GEMM, proven r4-r9).
__device__ __forceinline__ int swz(int row, int col) {
    return (row << 6) + ((((col >> 3) ^ row) & 7) << 3) + (col & 7);
}
// Swizzled index into [R][32] bf16 LDS tiles (BK=32 dbuf GEMM): 4 slots of
// 16B per 64B row; slot ^= (row>>1)&3 -> 2-way max (free) on b128 frag reads.
__device__ __forceinline__ int swz32(int r, int c) {
    return r * 32 + ((((c >> 3) ^ (r >> 1)) & 3) << 3) + (c & 7);
}
// Folded swizzle for attn K/V tiles (proven r6-r13).
__device__ __forceinline__ int swzf(int r, int d) {
    int row = r >> 1;
    int cs = ((r & 1) << 3) | (d >> 3);
    return row * 128 + ((cs ^ (row & 15)) << 3) + (d & 7);
}

__device__ __forceinline__ short8v pack8(const float* x) {
    union { unsigned int u[4]; short8v v; } r;
    r.u[0] = cvt_pk_bf16(x[0], x[1]);
    r.u[1] = cvt_pk_bf16(x[2], x[3]);
    r.u[2] = cvt_pk_bf16(x[4], x[5]);
    r.u[3] = cvt_pk_bf16(x[6], x[7]);
    return r.v;
}

// async global->LDS, 16B per lane; LDS dest wave-uniform base + lane*16.
__device__ __forceinline__ void gload16(const unsigned short* g,
                                        unsigned short* l) {
    __builtin_amdgcn_global_load_lds(
        (const __attribute__((address_space(1))) unsigned int*)(g),
        (__attribute__((address_space(3))) unsigned int*)(l), 16, 0, 0);
}

// ===========================================================================
// fp32 -> bf16 conversion of X, Wk, Wv, Wq(*QSC), Wo into ws; zero V pads.
// ===========================================================================
__global__ __launch_bounds__(256) void cvt_kernel(
    const float* __restrict__ X,  const float* __restrict__ Wk,
    const float* __restrict__ Wv, const float* __restrict__ Wq,
    const float* __restrict__ Wo, unsigned short* __restrict__ ws)
{
    size_t w = ((size_t)blockIdx.x * 256 + threadIdx.x) * 8;
    if (w >= CVT_TOTAL) {                 // pad-zero job (NaN-safety for PV)
        size_t p0 = w - CVT_TOTAL;
        unsigned short* Vt = ws + VT_OFF;
#pragma unroll
        for (int i = 0; i < 8; ++i) {
            size_t e = p0 + i;
            if (e < 16384u) {             // row pads: cols 1500..1503, 4096 rows
                size_t row = e >> 2;
                Vt[row * VSTR + 1500 + (e & 3)] = 0;
            } else if (e < PAD_ELEMS) {   // tail pad
                Vt[(size_t)4096 * VSTR + (e - 16384u)] = 0;
            }
        }
        return;
    }
    const float* s; unsigned short* d; float sc = 1.0f;
    if (w < 6144000u)      { s = X  + w;             d = ws + XB_OFF + w; }
    else if (w < 7192576u) { s = Wk + (w - 6144000u); d = ws + WB_OFF + (w - 6144000u); }
    else if (w < 8241152u) { s = Wv + (w - 7192576u); d = ws + WB_OFF + 1048576u + (w - 7192576u); }
    else if (w < 9289728u) { s = Wq + (w - 8241152u); d = ws + WB_OFF + 2097152u + (w - 8241152u); sc = QSC; }
    else                   { s = Wo + (w - 9289728u); d = ws + WOB_OFF + (w - 9289728u); }
    float t[8];
    *(float4*)t = *(const float4*)s;
    *(float4*)(t + 4) = *(const float4*)(s + 4);
#pragma unroll
    for (int i = 0; i < 8; ++i) t[i] *= sc;
    *(short8v*)d = pack8(t);
}

// ---------------------------------------------------------------------------
// r14 GEMM body: 128x128, BK=32, DOUBLE-BUFFERED global_load_lds (T3 minimal
// 2-phase). LDS total unchanged at 32KB (2 x 8KB per operand). Per step:
// issue next-tile loads -> frag-read current -> 16 MFMA -> one barrier
// (drains loads + read-hazards). Pre-swizzled global source (inverse swz32).
// ---------------------------------------------------------------------------
__device__ __forceinline__ void stage32(const unsigned short* __restrict__ Row,
                                        unsigned short* lbuf, int k0,
                                        int wv, int lane) {
#pragma unroll
    for (int g = 0; g < 2; ++g) {
        int j = g * 256 + wv * 64 + lane;      // chunk id 0..511
        int r = j >> 2;
        int s = (j & 3) ^ ((r >> 1) & 3);      // inverse-swz32 source slot
        gload16(Row + (size_t)r * E + k0 + s * 8,
                lbuf + (size_t)(g * 256 + wv * 64) * 8);
    }
}

__device__ __forceinline__ void gemm128db(
    const unsigned short* __restrict__ Arow,
    const unsigned short* __restrict__ Brow,
    unsigned short* As, unsigned short* Bs,   // each [2][128*32]
    int tid, f32x4 acc[4][4])
{
    const int lane = tid & 63, wv = tid >> 6;
    const int wm = tid >> 7, wn = (tid >> 6) & 1;
    stage32(Arow, As, 0, wv, lane);
    stage32(Brow, Bs, 0, wv, lane);
    __syncthreads();                          // buf0 ready
    int buf = 0;
    for (int k0 = 0; k0 < E; k0 += 32) {
        if (k0 + 32 < E) {                    // issue next tile (overlaps MFMA)
            stage32(Arow, As + (buf ^ 1) * 4096, k0 + 32, wv, lane);
            stage32(Brow, Bs + (buf ^ 1) * 4096, k0 + 32, wv, lane);
        }
        const unsigned short* Ab = As + buf * 4096;
        const unsigned short* Bb = Bs + buf * 4096;
        short8v afr[4], bfr[4];
#pragma unroll
        for (int m = 0; m < 4; ++m)
            afr[m] = *(const short8v*)(Ab + swz32(wm * 64 + m * 16 + (lane & 15),
                                                  (lane >> 4) * 8));
#pragma unroll
        for (int n = 0; n < 4; ++n)
            bfr[n] = *(const short8v*)(Bb + swz32(wn * 64 + n * 16 + (lane & 15),
                                                  (lane >> 4) * 8));
        __builtin_amdgcn_s_setprio(1);
#pragma unroll
        for (int m = 0; m < 4; ++m)
#pragma unroll
            for (int n = 0; n < 4; ++n)
                acc[m][n] = __builtin_amdgcn_mfma_f32_16x16x32_bf16(
                    afr[m], bfr[n], acc[m][n], 0, 0, 0);
        __builtin_amdgcn_s_setprio(0);
        __syncthreads();                      // next buf ready; reads done
        buf ^= 1;
    }
}

// Projections (fast): nb 0-7: K; 8-15: V(+bv, ->V^T stride VSTR); 16-23: Q.
__global__ __launch_bounds__(256) void proj_fast(
    const unsigned short* __restrict__ Xb, const unsigned short* __restrict__ Wb,
    const float* __restrict__ bv, const float* __restrict__ bq,
    unsigned short* __restrict__ Kb, unsigned short* __restrict__ Vt,
    unsigned short* __restrict__ Qa)
{
    __shared__ unsigned short As[2 * 128 * 32], Bs[2 * 128 * 32];
    const int sid = blockIdx.x;
    const int nid = (sid & 7) * 141 + (sid >> 3);        // T1 XCD-chunked
    const int mb = nid / 24, nb = nid % 24;
    const int z = nb >> 3;
    const size_t m0 = (size_t)mb * 128;
    const int tid = threadIdx.x, lane = tid & 63;
    const int wm = tid >> 7, wn = (tid >> 6) & 1;

    f32x4 acc[4][4];
#pragma unroll
    for (int m = 0; m < 4; ++m)
#pragma unroll
        for (int n = 0; n < 4; ++n)
#pragma unroll
            for (int i = 0; i < 4; ++i) acc[m][n][i] = 0.f;

    gemm128db(Xb + m0 * E, Wb + (size_t)nb * 128 * E, As, Bs, tid, acc);

#pragma unroll
    for (int m = 0; m < 4; ++m) {
        long gi0 = (long)m0 + wm * 64 + m * 16 + (lane >> 4) * 4;
#pragma unroll
        for (int n = 0; n < 4; ++n) {
            int col = (nb & 7) * 128 + wn * 64 + n * 16 + (lane & 15);
            if (z == 0) {
#pragma unroll
                for (int rg = 0; rg < 4; ++rg) {
                    long gi = gi0 + rg;
                    if (gi < M_) Kb[(size_t)gi * E + col] = f2bf(acc[m][n][rg]);
                }
            } else if (z == 2) {
                float bias = bq[col] * QSC;
#pragma unroll
                for (int rg = 0; rg < 4; ++rg) {
                    long gi = gi0 + rg;
                    if (gi < M_)
                        Qa[(size_t)gi * E + col] = f2bf(acc[m][n][rg] + bias);
                }
            } else {
                float bias = bv[col];
                if (gi0 + 3 < M_) {      // quad never crosses batch (SEQ_%4==0)
                    long bb = gi0 / SEQ_, t0 = gi0 % SEQ_;
                    union { unsigned int u[2]; ushort4v v; } pk;
                    pk.u[0] = cvt_pk_bf16(acc[m][n][0] + bias, acc[m][n][1] + bias);
                    pk.u[1] = cvt_pk_bf16(acc[m][n][2] + bias, acc[m][n][3] + bias);
                    *(ushort4v*)(Vt + ((size_t)bb * E + col) * VSTR + t0) = pk.v;
                } else {
#pragma unroll
                    for (int rg = 0; rg < 4; ++rg) {
                        long gi = gi0 + rg;
                        if (gi < M_) {
                            long bb = gi / SEQ_, t = gi % SEQ_;
                            Vt[((size_t)bb * E + col) * VSTR + t] =
                                f2bf(acc[m][n][rg] + bias);
                        }
                    }
                }
            }
        }
    }
}

// Output projection (fast): A = attn-out bf16 (Qa region), B = Wob bf16.
__global__ __launch_bounds__(256) void oproj_fast(
    const unsigned short* __restrict__ Ab, const unsigned short* __restrict__ Wob,
    const float* __restrict__ bo, float* __restrict__ out)
{
    __shared__ unsigned short As[2 * 128 * 32], Bs[2 * 128 * 32];
    const int sid = blockIdx.x;
    const int nid = (sid & 7) * 47 + (sid >> 3);         // 376 blocks
    const int mb = nid >> 3, nb = nid & 7;
    const size_t m0 = (size_t)mb * 128;
    const int tid = threadIdx.x, lane = tid & 63;
    const int wm = tid >> 7, wn = (tid >> 6) & 1;

    f32x4 acc[4][4];
#pragma unroll
    for (int m = 0; m < 4; ++m)
#pragma unroll
        for (int n = 0; n < 4; ++n)
#pragma unroll
            for (int i = 0; i < 4; ++i) acc[m][n][i] = 0.f;

    gemm128db(Ab + m0 * E, Wob + (size_t)nb * 128 * E, As, Bs, tid, acc);

#pragma unroll
    for (int m = 0; m < 4; ++m) {
        long gi0 = (long)m0 + wm * 64 + m * 16 + (lane >> 4) * 4;
#pragma unroll
        for (int n = 0; n < 4; ++n) {
            int col = nb * 128 + wn * 64 + n * 16 + (lane & 15);
            float bias = bo[col];
#pragma unroll
            for (int rg = 0; rg < 4; ++rg) {
                long gi = gi0 + rg;
                if (gi < M_) out[(size_t)gi * E + col] = acc[m][n][rg] + bias;
            }
        }
    }
}

// ===========================================================================
// Attention r14: r13's gload_lds staging + DOUBLE BUFFER (T3 minimal).
// Per tile: issue next-tile loads -> compute current -> one barrier.
// LDS 16->32.5KB. Math byte-identical to r13 (proven).
// ===========================================================================
__global__ __launch_bounds__(256, 4) void attn_gl(
    const unsigned short* __restrict__ Kb,   // [6000][1024] bf16 (d_out)
    const unsigned short* __restrict__ Vt,   // [4][1024][VSTR] bf16 (ws)
    unsigned short* __restrict__ Qa)         // Q in, attn-out overwrites
{
    __shared__ unsigned short ks[2][4096], vs[2][4096];   // 16KB + 16KB
    const int sid = blockIdx.x;
    const int nid = (sid & 7) * 96 + (sid >> 3);    // 768 blocks, 96/XCD
    const int bh = nid / 12, qb = nid % 12;
    const int b = bh >> 4, hh = bh & 15;
    const int tid = threadIdx.x, lane = tid & 63, wz = tid >> 6;
    const int c = lane & 31, g2 = lane >> 5;
    const int q0 = qb * 128 + wz * 32;

    const unsigned short* kbase = Kb + (size_t)b * SEQ_ * E + hh * 64;
    const unsigned short* vbase = Vt + ((size_t)b * E + hh * 64) * VSTR;

    // Stage one 64-key tile of K and V via global_load_lds into buffer bf.
    // 16B-chunk j holds swzf element-block (r, s): rp=j>>4, u=(j&15)^(rp&15),
    // r=2rp+(u>>3), s=u&7 (inverse-swzf, proven r13).
    auto stageKV = [&](int bf, int kt0) {
#pragma unroll
        for (int i = 0; i < 2; ++i) {
            int j = (i * 4 + wz) * 64 + lane;
            int rp = j >> 4;
            int u = (j & 15) ^ (rp & 15);
            int r = rp * 2 + (u >> 3);
            int s = u & 7;
            gload16(kbase + (size_t)(kt0 + r) * E + s * 8,
                    ks[bf] + (i * 4 + wz) * 512);
            gload16(vbase + (size_t)r * VSTR + kt0 + s * 8,
                    vs[bf] + (i * 4 + wz) * 512);
        }
    };

    // Q B-frags in registers: qf[t] holds q=q0+c, d = t*16 + 8*g2 + 0..7
    short8v qf[4];
    {
        int qr = q0 + c;
        bool ok = qr < SEQ_;
        const unsigned short* qp = Qa + ((size_t)b * SEQ_ + qr) * E + hh * 64 + 8 * g2;
#pragma unroll
        for (int t = 0; t < 4; ++t) {
            short8v zv;
#pragma unroll
            for (int i = 0; i < 8; ++i) zv[i] = 0;
            if (ok) zv = *(const short8v*)(qp + t * 16);
            qf[t] = zv;
        }
    }

    f32x16 o0, o1;
#pragma unroll
    for (int i = 0; i < 16; ++i) { o0[i] = 0.f; o1[i] = 0.f; }
    float lsum = 0.f;

    stageKV(0, 0);
    __syncthreads();                     // buf0 ready
    int buf = 0;

    const int NT = (SEQ_ + 63) / 64;     // 24
    for (int it = 0; it < NT; ++it) {
        const int kt0 = it * 64;
        if (it + 1 < NT) stageKV(buf ^ 1, kt0 + 64);   // overlap with compute
        const bool tail = (kt0 + 64 > SEQ_);
        const unsigned short* kcur = ks[buf];
        const unsigned short* vcur = vs[buf];

#pragma unroll
        for (int nt = 0; nt < 2; ++nt) {
            // S^T = mfma(K, Q): lane holds q=c, keys=(reg&3)+8*(reg>>2)+4*g2
            f32x16 s;
#pragma unroll
            for (int i = 0; i < 16; ++i) s[i] = 0.f;
            __builtin_amdgcn_s_setprio(1);
#pragma unroll
            for (int t = 0; t < 4; ++t) {
                short8v af = *(const short8v*)(kcur + swzf(nt * 32 + c, t * 16 + 8 * g2));
                s = __builtin_amdgcn_mfma_f32_32x32x16_bf16(af, qf[t], s, 0, 0, 0);
            }
            __builtin_amdgcn_s_setprio(0);
            if (tail) {
#pragma unroll
                for (int r = 0; r < 16; ++r) {
                    int key = kt0 + nt * 32 + (r & 3) + 8 * (r >> 2) + 4 * g2;
                    if (key >= SEQ_) s[r] = -1e30f;   // exp2 -> 0 (assignment)
                }
            }
            // max-free softmax fused with pack (scores |s|~O(3))
            unsigned int pk[8];
            float ls0 = 0.f, ls1 = 0.f;
#pragma unroll
            for (int h = 0; h < 8; ++h) {
                float p0 = __builtin_amdgcn_exp2f(s[2 * h]);
                float p1 = __builtin_amdgcn_exp2f(s[2 * h + 1]);
                if (h & 1) ls1 += p0 + p1; else ls0 += p0 + p1;
                pk[h] = cvt_pk_bf16(p0, p1);
            }
            lsum += ls0 + ls1;
            perml32(pk[0], pk[2]); perml32(pk[1], pk[3]);
            perml32(pk[4], pk[6]); perml32(pk[5], pk[7]);
            // PV
            __builtin_amdgcn_s_setprio(1);
#pragma unroll
            for (int tau = 0; tau < 2; ++tau) {
                union { unsigned int ww[4]; short8v v; } pa;
                pa.ww[0] = pk[4 * tau + 0];
                pa.ww[1] = pk[4 * tau + 1];
                pa.ww[2] = pk[4 * tau + 2];
                pa.ww[3] = pk[4 * tau + 3];
                int t = nt * 2 + tau;
                short8v vb0 = *(const short8v*)(vcur + swzf(0 + c, t * 16 + 8 * g2));
                short8v vb1 = *(const short8v*)(vcur + swzf(32 + c, t * 16 + 8 * g2));
                o0 = __builtin_amdgcn_mfma_f32_32x32x16_bf16(pa.v, vb0, o0, 0, 0, 0);
                o1 = __builtin_amdgcn_mfma_f32_32x32x16_bf16(pa.v, vb1, o1, 0, 0, 0);
            }
            __builtin_amdgcn_s_setprio(0);
        }

        __syncthreads();   // next buf loads drained; this buf's reads done
        buf ^= 1;
    }

    // epilogue (r13-proven): fold lsum halves, broadcast 1/lsum via LDS, store
    lsum += __shfl_xor(lsum, 32, 64);
    __syncthreads();
    float* lf = (float*)ks[0] + wz * 32;
    if (lane < 32) lf[c] = 1.0f / lsum;
#pragma unroll
    for (int r = 0; r < 16; ++r) {
        int ql = (r & 3) + 8 * (r >> 2) + 4 * g2;
        int tq = q0 + ql;
        if (tq < SEQ_) {
            float inv = lf[ql];
            unsigned short* op = Qa + ((size_t)b * SEQ_ + tq) * E + hh * 64;
            op[c] = f2bf(o0[r] * inv);
            op[32 + c] = f2bf(o1[r] * inv);
        }
    }
}

// ===========================================================================
// FALLBACK PATH (ws too small; not expected). r7 fp32-reg-staged GEMM +
// r9 LDS-staged attention, K|Vt(stride 1500) in d_out. Verbatim from r13.
// ===========================================================================
template <bool ABF>
__device__ __forceinline__ void gemm128(
    const float* __restrict__ Af, const unsigned short* __restrict__ Ab,
    size_t arow0, int avalid,
    const float* __restrict__ W, int wrow0,
    unsigned short* As, unsigned short* Bs,
    int tid, f32x4 acc[4][4])
{
    const int lane = tid & 63;
    const int wm = (tid >> 7), wn = (tid >> 6) & 1;
    float4 pA[8]; short8v pAb[4]; float4 pB[8];

    auto loadT = [&](int k0) {
#pragma unroll
        for (int uu = 0; uu < 4; ++uu) {
            int u = tid + uu * 256, row = u >> 3, sl = (u & 7) * 8;
            if constexpr (ABF) {
                short8v t;
#pragma unroll
                for (int i = 0; i < 8; ++i) t[i] = 0;
                if (row < avalid)
                    t = *(const short8v*)(Ab + (arow0 + row) * E + k0 + sl);
                pAb[uu] = t;
            } else {
                float4 x0 = make_float4(0.f, 0.f, 0.f, 0.f), x1 = x0;
                if (row < avalid) {
                    const float* p = Af + (arow0 + row) * (size_t)E + k0 + sl;
                    x0 = *(const float4*)p; x1 = *(const float4*)(p + 4);
                }
                pA[2 * uu] = x0; pA[2 * uu + 1] = x1;
            }
            const float* q = W + (size_t)(wrow0 + row) * E + k0 + sl;
            pB[2 * uu] = *(const float4*)q;
            pB[2 * uu + 1] = *(const float4*)(q + 4);
        }
    };
    auto commitT = [&]() {
#pragma unroll
        for (int uu = 0; uu < 4; ++uu) {
            int u = tid + uu * 256, row = u >> 3, sl = (u & 7) * 8;
            if constexpr (ABF) {
                *(short8v*)(As + swz(row, sl)) = pAb[uu];
            } else {
                float t[8];
                *(float4*)t = pA[2 * uu]; *(float4*)(t + 4) = pA[2 * uu + 1];
                *(short8v*)(As + swz(row, sl)) = pack8(t);
            }
            float t2[8];
            *(float4*)t2 = pB[2 * uu]; *(float4*)(t2 + 4) = pB[2 * uu + 1];
            *(short8v*)(Bs + swz(row, sl)) = pack8(t2);
        }
    };

    loadT(0);
    for (int k0 = 0; k0 < E; k0 += 64) {
        __syncthreads();
        commitT();
        __syncthreads();
        if (k0 + 64 < E) loadT(k0 + 64);
#pragma unroll
        for (int kk = 0; kk < 64; kk += 32) {
            short8v afr[4], bfr[4];
#pragma unroll
            for (int m = 0; m < 4; ++m)
                afr[m] = *(const short8v*)(As + swz(wm * 64 + m * 16 + (lane & 15),
                                                    kk + (lane >> 4) * 8));
#pragma unroll
            for (int n = 0; n < 4; ++n)
                bfr[n] = *(const short8v*)(Bs + swz(wn * 64 + n * 16 + (lane & 15),
                                                    kk + (lane >> 4) * 8));
            __builtin_amdgcn_s_setprio(1);
#pragma unroll
            for (int m = 0; m < 4; ++m)
#pragma unroll
                for (int n = 0; n < 4; ++n)
                    acc[m][n] = __builtin_amdgcn_mfma_f32_16x16x32_bf16(
                        afr[m], bfr[n], acc[m][n], 0, 0, 0);
            __builtin_amdgcn_s_setprio(0);
        }
    }
}

__global__ __launch_bounds__(256, 2) void proj_kernel(
    const float* __restrict__ X, const float* __restrict__ Wk,
    const float* __restrict__ Wv, const float* __restrict__ bv,
    const float* __restrict__ Wq, const float* __restrict__ bq,
    unsigned short* __restrict__ Kb, unsigned short* __restrict__ Vt,
    unsigned short* __restrict__ Qo)
{
    __shared__ unsigned short As[128 * 64], Bs[128 * 64];
    const int sid = blockIdx.x, cpx = gridDim.x >> 3;
    const int nid = (sid & 7) * cpx + (sid >> 3);
    const int mb = nid / 24, nb = nid % 24;
    const int z = nb >> 3, nbz = nb & 7;
    const size_t m0 = (size_t)mb * 128;
    const int avalid = (M_ - (int)m0) < 128 ? (M_ - (int)m0) : 128;
    const float* W = (z == 0) ? Wk : (z == 1) ? Wv : Wq;

    f32x4 acc[4][4];
#pragma unroll
    for (int m = 0; m < 4; ++m)
#pragma unroll
        for (int n = 0; n < 4; ++n)
#pragma unroll
            for (int i = 0; i < 4; ++i) acc[m][n][i] = 0.f;

    gemm128<false>(X, nullptr, m0, avalid, W, nbz * 128, As, Bs, threadIdx.x, acc);

    const int tid = threadIdx.x, lane = tid & 63;
    const int wm = (tid >> 7), wn = (tid >> 6) & 1;
#pragma unroll
    for (int m = 0; m < 4; ++m) {
        long gi0 = (long)m0 + wm * 64 + m * 16 + (lane >> 4) * 4;
#pragma unroll
        for (int n = 0; n < 4; ++n) {
            int col = nbz * 128 + wn * 64 + n * 16 + (lane & 15);
            if (z == 0) {
#pragma unroll
                for (int rg = 0; rg < 4; ++rg) {
                    long gi = gi0 + rg;
                    if (gi < M_) Kb[(size_t)gi * E + col] = f2bf(acc[m][n][rg]);
                }
            } else if (z == 2) {
                float bias = bq[col];
#pragma unroll
                for (int rg = 0; rg < 4; ++rg) {
                    long gi = gi0 + rg;
                    if (gi < M_)
                        Qo[(size_t)gi * E + col] = f2bf((acc[m][n][rg] + bias) * QSC);
                }
            } else {
                float bias = bv[col];
                if (gi0 + 3 < M_) {
                    long bb = gi0 / SEQ_, t0 = gi0 % SEQ_;
                    union { unsigned int u[2]; ushort4v v; } pk;
                    pk.u[0] = cvt_pk_bf16(acc[m][n][0] + bias, acc[m][n][1] + bias);
                    pk.u[1] = cvt_pk_bf16(acc[m][n][2] + bias, acc[m][n][3] + bias);
                    *(ushort4v*)(Vt + ((size_t)bb * E + col) * SEQ_ + t0) = pk.v;
                } else {
#pragma unroll
                    for (int rg = 0; rg < 4; ++rg) {
                        long gi = gi0 + rg;
                        if (gi < M_) {
                            long bb = gi / SEQ_, t = gi % SEQ_;
                            Vt[((size_t)bb * E + col) * SEQ_ + t] =
                                f2bf(acc[m][n][rg] + bias);
                        }
                    }
                }
            }
        }
    }
}

__global__ __launch_bounds__(256, 2) void oproj_kernel(
    const unsigned short* __restrict__ Ab, const float* __restrict__ Wo,
    const float* __restrict__ bo, float* __restrict__ out)
{
    __shared__ unsigned short As[128 * 64], Bs[128 * 64];
    const int sid = blockIdx.x, cpx = gridDim.x >> 3;
    const int nid = (sid & 7) * cpx + (sid >> 3);
    const int mb = nid >> 3, nb = nid & 7;
    const size_t m0 = (size_t)mb * 128;
    const int avalid = (M_ - (int)m0) < 128 ? (M_ - (int)m0) : 128;

    f32x4 acc[4][4];
#pragma unroll
    for (int m = 0; m < 4; ++m)
#pragma unroll
        for (int n = 0; n < 4; ++n)
#pragma unroll
            for (int i = 0; i < 4; ++i) acc[m][n][i] = 0.f;

    gemm128<true>(nullptr, Ab, m0, avalid, Wo, nb * 128, As, Bs, threadIdx.x, acc);

    const int tid = threadIdx.x, lane = tid & 63;
    const int wm = (tid >> 7), wn = (tid >> 6) & 1;
#pragma unroll
    for (int m = 0; m < 4; ++m) {
        long gi0 = (long)m0 + wm * 64 + m * 16 + (lane >> 4) * 4;
#pragma unroll
        for (int n = 0; n < 4; ++n) {
            int col = nb * 128 + wn * 64 + n * 16 + (lane & 15);
            float bias = bo[col];
#pragma unroll
            for (int rg = 0; rg < 4; ++rg) {
                long gi = gi0 + rg;
                if (gi < M_) out[(size_t)gi * E + col] = acc[m][n][rg] + bias;
            }
        }
    }
}

__global__ __launch_bounds__(256, 4) void attn_fallback(
    const unsigned short* __restrict__ Kb,
    const unsigned short* __restrict__ Vt,
    unsigned short* __restrict__ Qa)
{
    __shared__ unsigned short ks[2][32 * 128], vs[2][32 * 128];
    const int sid = blockIdx.x;
    const int nid = (sid & 7) * 96 + (sid >> 3);
    const int bh = nid / 12, qb = nid % 12;
    const int b = bh >> 4, hh = bh & 15;
    const int tid = threadIdx.x, lane = tid & 63, wz = tid >> 6;
    const int c = lane & 31, g2 = lane >> 5;
    const int q0 = qb * 128 + wz * 32;

    const unsigned short* kbase = Kb + (size_t)b * SEQ_ * E + hh * 64;
    const unsigned short* vbase = Vt + ((size_t)b * E + hh * 64) * SEQ_;

    short8v kreg[2];
    ushort4v vreg[4];
    auto loadK = [&](int kt0) {
#pragma unroll
        for (int uu = 0; uu < 2; ++uu) {
            int u = tid + uu * 256, key = u >> 3, slot = (u & 7) * 8;
            short8v t;
#pragma unroll
            for (int i = 0; i < 8; ++i) t[i] = 0;
            int gk = kt0 + key;
            if (gk < SEQ_) t = *(const short8v*)(kbase + (size_t)gk * E + slot);
            kreg[uu] = t;
        }
    };
    auto loadV = [&](int kt0) {
#pragma unroll
        for (int uu = 0; uu < 4; ++uu) {
            int u = tid + uu * 256, d = u >> 4, q4 = (u & 15) * 4;
            ushort4v t; t[0] = t[1] = t[2] = t[3] = 0;
            int col = kt0 + q4, rem = SEQ_ - col;
            const unsigned short* src = vbase + (size_t)d * SEQ_ + col;
            if (rem >= 4) t = *(const ushort4v*)src;
            else if (rem > 0) { for (int e2 = 0; e2 < 4; ++e2) if (e2 < rem) t[e2] = src[e2]; }
            vreg[uu] = t;
        }
    };
    auto commitKV = [&](unsigned short* kd, unsigned short* vd) {
#pragma unroll
        for (int uu = 0; uu < 2; ++uu) {
            int u = tid + uu * 256;
            *(short8v*)(kd + swzf(u >> 3, (u & 7) * 8)) = kreg[uu];
        }
#pragma unroll
        for (int uu = 0; uu < 4; ++uu) {
            int u = tid + uu * 256;
            *(ushort4v*)(vd + swzf(u >> 4, (u & 15) * 4)) = vreg[uu];
        }
    };

    loadK(0); loadV(0);

    short8v qf[4];
    {
        int qr = q0 + c;
        bool ok = qr < SEQ_;
        const unsigned short* qp = Qa + ((size_t)b * SEQ_ + qr) * E + hh * 64 + 8 * g2;
#pragma unroll
        for (int t = 0; t < 4; ++t) {
            short8v zv;
#pragma unroll
            for (int i = 0; i < 8; ++i) zv[i] = 0;
            if (ok) zv = *(const short8v*)(qp + t * 16);
            qf[t] = zv;
        }
    }

    f32x16 o0, o1;
#pragma unroll
    for (int i = 0; i < 16; ++i) { o0[i] = 0.f; o1[i] = 0.f; }
    float lsum = 0.f;

    commitKV(ks[0], vs[0]);
    __syncthreads();
    loadK(64); loadV(64);

    const int NT = (SEQ_ + 63) / 64;     // 24
    for (int it = 0; it < NT; ++it) {
        const int kt0 = it * 64;
        const unsigned short* kcur = ks[it & 1];
        const unsigned short* vcur = vs[it & 1];
        const bool tail = (kt0 + 64 > SEQ_);

#pragma unroll
        for (int nt = 0; nt < 2; ++nt) {
            f32x16 s;
#pragma unroll
            for (int i = 0; i < 16; ++i) s[i] = 0.f;
#pragma unroll
            for (int t = 0; t < 4; ++t) {
                short8v af = *(const short8v*)(kcur + swzf(nt * 32 + c, t * 16 + 8 * g2));
                s = __builtin_amdgcn_mfma_f32_32x32x16_bf16(af, qf[t], s, 0, 0, 0);
            }
            if (tail) {
#pragma unroll
                for (int r = 0; r < 16; ++r) {
                    int key = kt0 + nt * 32 + (r & 3) + 8 * (r >> 2) + 4 * g2;
                    if (key >= SEQ_) s[r] = -1e30f;
                }
            }
            unsigned int pk[8];
            float ls0 = 0.f, ls1 = 0.f;
#pragma unroll
            for (int h = 0; h < 8; ++h) {
                float p0 = __builtin_amdgcn_exp2f(s[2 * h]);
                float p1 = __builtin_amdgcn_exp2f(s[2 * h + 1]);
                if (h & 1) ls1 += p0 + p1; else ls0 += p0 + p1;
                pk[h] = cvt_pk_bf16(p0, p1);
            }
            lsum += ls0 + ls1;
            perml32(pk[0], pk[2]); perml32(pk[1], pk[3]);
            perml32(pk[4], pk[6]); perml32(pk[5], pk[7]);
#pragma unroll
            for (int tau = 0; tau < 2; ++tau) {
                union { unsigned int ww[4]; short8v v; } pa;
                pa.ww[0] = pk[4 * tau + 0];
                pa.ww[1] = pk[4 * tau + 1];
                pa.ww[2] = pk[4 * tau + 2];
                pa.ww[3] = pk[4 * tau + 3];
                int t = nt * 2 + tau;
                short8v vb0 = *(const short8v*)(vcur + swzf(0 + c, t * 16 + 8 * g2));
                short8v vb1 = *(const short8v*)(vcur + swzf(32 + c, t * 16 + 8 * g2));
                o0 = __builtin_amdgcn_mfma_f32_32x32x16_bf16(pa.v, vb0, o0, 0, 0, 0);
                o1 = __builtin_amdgcn_mfma_f32_32x32x16_bf16(pa.v, vb1, o1, 0, 0, 0);
            }
        }

        if (it + 1 < NT) {
            commitKV(ks[(it + 1) & 1], vs[(it + 1) & 1]);
            __syncthreads();
            if (it + 2 < NT) { loadK(kt0 + 128); loadV(kt0 + 128); }
        }
    }

    lsum += __shfl_xor(lsum, 32, 64);
    __syncthreads();
    float* lf = (float*)ks[0] + wz * 32;
    if (lane < 32) lf[c] = 1.0f / lsum;
#pragma unroll
    for (int r = 0; r < 16; ++r) {
        int ql = (r & 3) + 8 * (r >> 2) + 4 * g2;
        int tq = q0 + ql;
        if (tq < SEQ_) {
            float inv = lf[ql];
            unsigned short* op = Qa + ((size_t)b * SEQ_ + tq) * E + hh * 64;
            op[c] = f2bf(o0[r] * inv);
            op[32 + c] = f2bf(o1[r] * inv);
        }
    }
}

extern "C" void kernel_launch(void* const* d_in, const int* in_sizes, int n_in,
                              void* d_out, int out_size, void* d_ws, size_t ws_size,
                              hipStream_t stream) {
    const float* hs = (const float*)d_in[0];
    const float* Wq = (const float*)d_in[1];
    const float* bq = (const float*)d_in[2];
    const float* Wk = (const float*)d_in[3];
    const float* Wv = (const float*)d_in[4];
    const float* bv = (const float*)d_in[5];
    const float* Wo = (const float*)d_in[6];
    const float* bo = (const float*)d_in[7];

    unsigned short* Kb = (unsigned short*)d_out;     // K bf16, overwritten by oproj
    unsigned short* ws = (unsigned short*)d_ws;
    unsigned short* Qa = ws + QA_OFF;
    float* out = (float*)d_out;

    if (ws_size >= WS_FAST_BYTES) {
        unsigned short* Vt = ws + VT_OFF;            // padded V^T in ws
        cvt_kernel<<<dim3(5057), 256, 0, stream>>>(hs, Wk, Wv, Wq, Wo, ws);
        proj_fast<<<dim3(1128), 256, 0, stream>>>(ws + XB_OFF, ws + WB_OFF,
                                                  bv, bq, Kb, Vt, Qa);
        attn_gl<<<dim3(768), 256, 0, stream>>>(Kb, Vt, Qa);
        oproj_fast<<<dim3(376), 256, 0, stream>>>(Qa, ws + WOB_OFF, bo, out);
    } else {
        // fallback: r7 proj + r9 attn, K|Vt(stride 1500) in d_out
        unsigned short* Vt = (unsigned short*)d_out + SZE;
        proj_kernel<<<dim3(47 * 24), 256, 0, stream>>>(hs, Wk, Wv, bv, Wq, bq,
                                                       Kb, Vt, Qa);
        attn_fallback<<<dim3(768), 256, 0, stream>>>(Kb, Vt, Qa);
        oproj_kernel<<<dim3(47 * 8), 256, 0, stream>>>(Qa, Wo, bo, out);
    }
}

// Round 18
// 146.142 us; speedup vs baseline: 2.1564x; 1.0007x over previous
//
#include <hip/hip_runtime.h>
#include <math.h>

#define E 1024
#define NH 16
#define HD 64
#define BSZ_ 4
#define SEQ_ 1500
#define VSTR 1504                        // padded V^T row stride (16B-aligned)
#define M_ (BSZ_ * SEQ_)                 // 6000
#define SZE ((size_t)M_ * (size_t)E)     // 6,144,000
#define QSC (0.125f * 1.44269504f)       // fold log2e: P = exp2(s)

// ws layout (ushort offsets), fast path:
#define QA_OFF  0u                        // Q / attn-out bf16 [6000][1024]
#define XB_OFF  6144000u                  // X bf16 [6000][1024]
#define WB_OFF  12288000u                 // [Wk;Wv;Wq*QSC] bf16 [3072][1024]
#define WOB_OFF 15433728u                 // Wo bf16 [1024][1024]
#define VT_OFF  16482304u                 // V^T bf16 [4][1024][VSTR] + 2048 pad
#define CVT_TOTAL 10338304u               // elems converted by cvt
#define PAD_ELEMS 18432u                  // 4096*4 row-pad + 2048 tail-pad
#define WS_FAST_BYTES 45289472ull         // (VT_OFF + 4096*VSTR + 2048)*2

typedef __attribute__((ext_vector_type(8))) short short8v;    // 8 bf16
typedef __attribute__((ext_vector_type(4))) float f32x4;
typedef __attribute__((ext_vector_type(16))) float f32x16;
typedef __attribute__((ext_vector_type(4))) unsigned short ushort4v;

__device__ __forceinline__ unsigned short f2bf(float f) {
    union { float f; unsigned int i; } c; c.f = f;
    return (unsigned short)((c.i + 0x7FFFu + ((c.i >> 16) & 1u)) >> 16);
}
__device__ __forceinline__ unsigned int cvt_pk_bf16(float a, float b) {
    unsigned int r;
    asm("v_cvt_pk_bf16_f32 %0, %1, %2" : "=v"(r) : "v"(a), "v"(b));
    return r;
}
// v_permlane32_swap_b32: a'[l] = l<32 ? a[l] : b[l-32]; b'[l] = l<32 ? a[l+32] : b[l]
__device__ __forceinline__ void perml32(unsigned int &a, unsigned int &b) {
    asm("v_permlane32_swap_b32 %0, %1" : "+v"(a), "+v"(b));
}

// Swizzled index into [R][64] bf16 LDS tiles (fallback GEMM, proven r4-r9).
__device__ __forceinline__ int swz(int row, int col) {
    return (row << 6) + ((((col >> 3) ^ row) & 7) << 3) + (col & 7);
}
// Swizzled index into [R][32] bf16 LDS tiles (BK=32 dbuf GEMM, proven r14).
__device__ __forceinline__ int swz32(int r, int c) {
    return r * 32 + ((((c >> 3) ^ (r >> 1)) & 3) << 3) + (c & 7);
}
// Folded swizzle for attn K/V tiles (proven r6-r14).
__device__ __forceinline__ int swzf(int r, int d) {
    int row = r >> 1;
    int cs = ((r & 1) << 3) | (d >> 3);
    return row * 128 + ((cs ^ (row & 15)) << 3) + (d & 7);
}

__device__ __forceinline__ short8v pack8(const float* x) {
    union { unsigned int u[4]; short8v v; } r;
    r.u[0] = cvt_pk_bf16(x[0], x[1]);
    r.u[1] = cvt_pk_bf16(x[2], x[3]);
    r.u[2] = cvt_pk_bf16(x[4], x[5]);
    r.u[3] = cvt_pk_bf16(x[6], x[7]);
    return r.v;
}

// async global->LDS, 16B per lane; LDS dest wave-uniform base + lane*16.
__device__ __forceinline__ void gload16(const unsigned short* g,
                                        unsigned short* l) {
    __builtin_amdgcn_global_load_lds(
        (const __attribute__((address_space(1))) unsigned int*)(g),
        (__attribute__((address_space(3))) unsigned int*)(l), 16, 0, 0);
}

// ===========================================================================
// fp32 -> bf16 conversion of X, Wk, Wv, Wq(*QSC), Wo into ws; zero V pads.
// ===========================================================================
__global__ __launch_bounds__(256) void cvt_kernel(
    const float* __restrict__ X,  const float* __restrict__ Wk,
    const float* __restrict__ Wv, const float* __restrict__ Wq,
    const float* __restrict__ Wo, unsigned short* __restrict__ ws)
{
    size_t w = ((size_t)blockIdx.x * 256 + threadIdx.x) * 8;
    if (w >= CVT_TOTAL) {                 // pad-zero job (NaN-safety for PV)
        size_t p0 = w - CVT_TOTAL;
        unsigned short* Vt = ws + VT_OFF;
#pragma unroll
        for (int i = 0; i < 8; ++i) {
            size_t e = p0 + i;
            if (e < 16384u) {             // row pads: cols 1500..1503, 4096 rows
                size_t row = e >> 2;
                Vt[row * VSTR + 1500 + (e & 3)] = 0;
            } else if (e < PAD_ELEMS) {   // tail pad
                Vt[(size_t)4096 * VSTR + (e - 16384u)] = 0;
            }
        }
        return;
    }
    const float* s; unsigned short* d; float sc = 1.0f;
    if (w < 6144000u)      { s = X  + w;             d = ws + XB_OFF + w; }
    else if (w < 7192576u) { s = Wk + (w - 6144000u); d = ws + WB_OFF + (w - 6144000u); }
    else if (w < 8241152u) { s = Wv + (w - 7192576u); d = ws + WB_OFF + 1048576u + (w - 7192576u); }
    else if (w < 9289728u) { s = Wq + (w - 8241152u); d = ws + WB_OFF + 2097152u + (w - 8241152u); sc = QSC; }
    else                   { s = Wo + (w - 9289728u); d = ws + WOB_OFF + (w - 9289728u); }
    float t[8];
    *(float4*)t = *(const float4*)s;
    *(float4*)(t + 4) = *(const float4*)(s + 4);
#pragma unroll
    for (int i = 0; i < 8; ++i) t[i] *= sc;
    *(short8v*)d = pack8(t);
}

// ---------------------------------------------------------------------------
// r14 GEMM body (proven 146us): 128x128, BK=32, double-buffered
// global_load_lds. Per step: issue next-tile loads -> frag-read current ->
// 16 MFMA -> one __syncthreads (drains loads + read hazards).
// ---------------------------------------------------------------------------
__device__ __forceinline__ void stage32(const unsigned short* __restrict__ Row,
                                        unsigned short* lbuf, int k0,
                                        int wv, int lane) {
#pragma unroll
    for (int g = 0; g < 2; ++g) {
        int j = g * 256 + wv * 64 + lane;      // chunk id 0..511
        int r = j >> 2;
        int s = (j & 3) ^ ((r >> 1) & 3);      // inverse-swz32 source slot
        gload16(Row + (size_t)r * E + k0 + s * 8,
                lbuf + (size_t)(g * 256 + wv * 64) * 8);
    }
}

__device__ __forceinline__ void gemm128db(
    const unsigned short* __restrict__ Arow,
    const unsigned short* __restrict__ Brow,
    unsigned short* As, unsigned short* Bs,   // each [2][128*32]
    int tid, f32x4 acc[4][4])
{
    const int lane = tid & 63, wv = tid >> 6;
    const int wm = tid >> 7, wn = (tid >> 6) & 1;
    stage32(Arow, As, 0, wv, lane);
    stage32(Brow, Bs, 0, wv, lane);
    __syncthreads();                          // buf0 ready
    int buf = 0;
    for (int k0 = 0; k0 < E; k0 += 32) {
        if (k0 + 32 < E) {                    // issue next tile (overlaps MFMA)
            stage32(Arow, As + (buf ^ 1) * 4096, k0 + 32, wv, lane);
            stage32(Brow, Bs + (buf ^ 1) * 4096, k0 + 32, wv, lane);
        }
        const unsigned short* Ab = As + buf * 4096;
        const unsigned short* Bb = Bs + buf * 4096;
        short8v afr[4], bfr[4];
#pragma unroll
        for (int m = 0; m < 4; ++m)
            afr[m] = *(const short8v*)(Ab + swz32(wm * 64 + m * 16 + (lane & 15),
                                                  (lane >> 4) * 8));
#pragma unroll
        for (int n = 0; n < 4; ++n)
            bfr[n] = *(const short8v*)(Bb + swz32(wn * 64 + n * 16 + (lane & 15),
                                                  (lane >> 4) * 8));
        __builtin_amdgcn_s_setprio(1);
#pragma unroll
        for (int m = 0; m < 4; ++m)
#pragma unroll
            for (int n = 0; n < 4; ++n)
                acc[m][n] = __builtin_amdgcn_mfma_f32_16x16x32_bf16(
                    afr[m], bfr[n], acc[m][n], 0, 0, 0);
        __builtin_amdgcn_s_setprio(0);
        __syncthreads();                      // next buf ready; reads done
        buf ^= 1;
    }
}

// Projections (fast): nb 0-7: K; 8-15: V(+bv, ->V^T stride VSTR); 16-23: Q.
__global__ __launch_bounds__(256) void proj_fast(
    const unsigned short* __restrict__ Xb, const unsigned short* __restrict__ Wb,
    const float* __restrict__ bv, const float* __restrict__ bq,
    unsigned short* __restrict__ Kb, unsigned short* __restrict__ Vt,
    unsigned short* __restrict__ Qa)
{
    __shared__ unsigned short As[2 * 128 * 32], Bs[2 * 128 * 32];
    const int sid = blockIdx.x;
    const int nid = (sid & 7) * 141 + (sid >> 3);        // T1 XCD-chunked
    const int mb = nid / 24, nb = nid % 24;
    const int z = nb >> 3;
    const size_t m0 = (size_t)mb * 128;
    const int tid = threadIdx.x, lane = tid & 63;
    const int wm = tid >> 7, wn = (tid >> 6) & 1;

    f32x4 acc[4][4];
#pragma unroll
    for (int m = 0; m < 4; ++m)
#pragma unroll
        for (int n = 0; n < 4; ++n)
#pragma unroll
            for (int i = 0; i < 4; ++i) acc[m][n][i] = 0.f;

    gemm128db(Xb + m0 * E, Wb + (size_t)nb * 128 * E, As, Bs, tid, acc);

#pragma unroll
    for (int m = 0; m < 4; ++m) {
        long gi0 = (long)m0 + wm * 64 + m * 16 + (lane >> 4) * 4;
#pragma unroll
        for (int n = 0; n < 4; ++n) {
            int col = (nb & 7) * 128 + wn * 64 + n * 16 + (lane & 15);
            if (z == 0) {
#pragma unroll
                for (int rg = 0; rg < 4; ++rg) {
                    long gi = gi0 + rg;
                    if (gi < M_) Kb[(size_t)gi * E + col] = f2bf(acc[m][n][rg]);
                }
            } else if (z == 2) {
                float bias = bq[col] * QSC;
#pragma unroll
                for (int rg = 0; rg < 4; ++rg) {
                    long gi = gi0 + rg;
                    if (gi < M_)
                        Qa[(size_t)gi * E + col] = f2bf(acc[m][n][rg] + bias);
                }
            } else {
                float bias = bv[col];
                if (gi0 + 3 < M_) {      // quad never crosses batch (SEQ_%4==0)
                    long bb = gi0 / SEQ_, t0 = gi0 % SEQ_;
                    union { unsigned int u[2]; ushort4v v; } pk;
                    pk.u[0] = cvt_pk_bf16(acc[m][n][0] + bias, acc[m][n][1] + bias);
                    pk.u[1] = cvt_pk_bf16(acc[m][n][2] + bias, acc[m][n][3] + bias);
                    *(ushort4v*)(Vt + ((size_t)bb * E + col) * VSTR + t0) = pk.v;
                } else {
#pragma unroll
                    for (int rg = 0; rg < 4; ++rg) {
                        long gi = gi0 + rg;
                        if (gi < M_) {
                            long bb = gi / SEQ_, t = gi % SEQ_;
                            Vt[((size_t)bb * E + col) * VSTR + t] =
                                f2bf(acc[m][n][rg] + bias);
                        }
                    }
                }
            }
        }
    }
}

// Output projection (fast): A = attn-out bf16 (Qa region), B = Wob bf16.
__global__ __launch_bounds__(256) void oproj_fast(
    const unsigned short* __restrict__ Ab, const unsigned short* __restrict__ Wob,
    const float* __restrict__ bo, float* __restrict__ out)
{
    __shared__ unsigned short As[2 * 128 * 32], Bs[2 * 128 * 32];
    const int sid = blockIdx.x;
    const int nid = (sid & 7) * 47 + (sid >> 3);         // 376 blocks
    const int mb = nid >> 3, nb = nid & 7;
    const size_t m0 = (size_t)mb * 128;
    const int tid = threadIdx.x, lane = tid & 63;
    const int wm = tid >> 7, wn = (tid >> 6) & 1;

    f32x4 acc[4][4];
#pragma unroll
    for (int m = 0; m < 4; ++m)
#pragma unroll
        for (int n = 0; n < 4; ++n)
#pragma unroll
            for (int i = 0; i < 4; ++i) acc[m][n][i] = 0.f;

    gemm128db(Ab + m0 * E, Wob + (size_t)nb * 128 * E, As, Bs, tid, acc);

#pragma unroll
    for (int m = 0; m < 4; ++m) {
        long gi0 = (long)m0 + wm * 64 + m * 16 + (lane >> 4) * 4;
#pragma unroll
        for (int n = 0; n < 4; ++n) {
            int col = nb * 128 + wn * 64 + n * 16 + (lane & 15);
            float bias = bo[col];
#pragma unroll
            for (int rg = 0; rg < 4; ++rg) {
                long gi = gi0 + rg;
                if (gi < M_) out[(size_t)gi * E + col] = acc[m][n][rg] + bias;
            }
        }
    }
}

// ===========================================================================
// Attention r14 (proven): gload_lds staging + double buffer, one
// __syncthreads per tile. Math byte-identical to r13 (proven).
// ===========================================================================
__global__ __launch_bounds__(256, 4) void attn_gl(
    const unsigned short* __restrict__ Kb,   // [6000][1024] bf16 (d_out)
    const unsigned short* __restrict__ Vt,   // [4][1024][VSTR] bf16 (ws)
    unsigned short* __restrict__ Qa)         // Q in, attn-out overwrites
{
    __shared__ unsigned short ks[2][4096], vs[2][4096];   // 16KB + 16KB
    const int sid = blockIdx.x;
    const int nid = (sid & 7) * 96 + (sid >> 3);    // 768 blocks, 96/XCD
    const int bh = nid / 12, qb = nid % 12;
    const int b = bh >> 4, hh = bh & 15;
    const int tid = threadIdx.x, lane = tid & 63, wz = tid >> 6;
    const int c = lane & 31, g2 = lane >> 5;
    const int q0 = qb * 128 + wz * 32;

    const unsigned short* kbase = Kb + (size_t)b * SEQ_ * E + hh * 64;
    const unsigned short* vbase = Vt + ((size_t)b * E + hh * 64) * VSTR;

    // Stage one 64-key tile of K and V via global_load_lds into buffer bf.
    // 16B-chunk j holds swzf element-block (r, s): rp=j>>4, u=(j&15)^(rp&15),
    // r=2rp+(u>>3), s=u&7 (inverse-swzf, proven r13).
    auto stageKV = [&](int bf, int kt0) {
#pragma unroll
        for (int i = 0; i < 2; ++i) {
            int j = (i * 4 + wz) * 64 + lane;
            int rp = j >> 4;
            int u = (j & 15) ^ (rp & 15);
            int r = rp * 2 + (u >> 3);
            int s = u & 7;
            gload16(kbase + (size_t)(kt0 + r) * E + s * 8,
                    ks[bf] + (i * 4 + wz) * 512);
            gload16(vbase + (size_t)r * VSTR + kt0 + s * 8,
                    vs[bf] + (i * 4 + wz) * 512);
        }
    };

    // Q B-frags in registers: qf[t] holds q=q0+c, d = t*16 + 8*g2 + 0..7
    short8v qf[4];
    {
        int qr = q0 + c;
        bool ok = qr < SEQ_;
        const unsigned short* qp = Qa + ((size_t)b * SEQ_ + qr) * E + hh * 64 + 8 * g2;
#pragma unroll
        for (int t = 0; t < 4; ++t) {
            short8v zv;
#pragma unroll
            for (int i = 0; i < 8; ++i) zv[i] = 0;
            if (ok) zv = *(const short8v*)(qp + t * 16);
            qf[t] = zv;
        }
    }

    f32x16 o0, o1;
#pragma unroll
    for (int i = 0; i < 16; ++i) { o0[i] = 0.f; o1[i] = 0.f; }
    float lsum = 0.f;

    stageKV(0, 0);
    __syncthreads();                     // buf0 ready
    int buf = 0;

    const int NT = (SEQ_ + 63) / 64;     // 24
    for (int it = 0; it < NT; ++it) {
        const int kt0 = it * 64;
        if (it + 1 < NT) stageKV(buf ^ 1, kt0 + 64);   // overlap with compute
        const bool tail = (kt0 + 64 > SEQ_);
        const unsigned short* kcur = ks[buf];
        const unsigned short* vcur = vs[buf];

#pragma unroll
        for (int nt = 0; nt < 2; ++nt) {
            // S^T = mfma(K, Q): lane holds q=c, keys=(reg&3)+8*(reg>>2)+4*g2
            f32x16 s;
#pragma unroll
            for (int i = 0; i < 16; ++i) s[i] = 0.f;
            __builtin_amdgcn_s_setprio(1);
#pragma unroll
            for (int t = 0; t < 4; ++t) {
                short8v af = *(const short8v*)(kcur + swzf(nt * 32 + c, t * 16 + 8 * g2));
                s = __builtin_amdgcn_mfma_f32_32x32x16_bf16(af, qf[t], s, 0, 0, 0);
            }
            __builtin_amdgcn_s_setprio(0);
            if (tail) {
#pragma unroll
                for (int r = 0; r < 16; ++r) {
                    int key = kt0 + nt * 32 + (r & 3) + 8 * (r >> 2) + 4 * g2;
                    if (key >= SEQ_) s[r] = -1e30f;   // exp2 -> 0 (assignment)
                }
            }
            // max-free softmax fused with pack (scores |s|~O(3))
            unsigned int pk[8];
            float ls0 = 0.f, ls1 = 0.f;
#pragma unroll
            for (int h = 0; h < 8; ++h) {
                float p0 = __builtin_amdgcn_exp2f(s[2 * h]);
                float p1 = __builtin_amdgcn_exp2f(s[2 * h + 1]);
                if (h & 1) ls1 += p0 + p1; else ls0 += p0 + p1;
                pk[h] = cvt_pk_bf16(p0, p1);
            }
            lsum += ls0 + ls1;
            perml32(pk[0], pk[2]); perml32(pk[1], pk[3]);
            perml32(pk[4], pk[6]); perml32(pk[5], pk[7]);
            // PV
            __builtin_amdgcn_s_setprio(1);
#pragma unroll
            for (int tau = 0; tau < 2; ++tau) {
                union { unsigned int ww[4]; short8v v; } pa;
                pa.ww[0] = pk[4 * tau + 0];
                pa.ww[1] = pk[4 * tau + 1];
                pa.ww[2] = pk[4 * tau + 2];
                pa.ww[3] = pk[4 * tau + 3];
                int t = nt * 2 + tau;
                short8v vb0 = *(const short8v*)(vcur + swzf(0 + c, t * 16 + 8 * g2));
                short8v vb1 = *(const short8v*)(vcur + swzf(32 + c, t * 16 + 8 * g2));
                o0 = __builtin_amdgcn_mfma_f32_32x32x16_bf16(pa.v, vb0, o0, 0, 0, 0);
                o1 = __builtin_amdgcn_mfma_f32_32x32x16_bf16(pa.v, vb1, o1, 0, 0, 0);
            }
            __builtin_amdgcn_s_setprio(0);
        }

        __syncthreads();   // next buf loads drained; this buf's reads done
        buf ^= 1;
    }

    // epilogue (r13-proven): fold lsum halves, broadcast 1/lsum via LDS, store
    lsum += __shfl_xor(lsum, 32, 64);
    __syncthreads();
    float* lf = (float*)ks[0] + wz * 32;
    if (lane < 32) lf[c] = 1.0f / lsum;
#pragma unroll
    for (int r = 0; r < 16; ++r) {
        int ql = (r & 3) + 8 * (r >> 2) + 4 * g2;
        int tq = q0 + ql;
        if (tq < SEQ_) {
            float inv = lf[ql];
            unsigned short* op = Qa + ((size_t)b * SEQ_ + tq) * E + hh * 64;
            op[c] = f2bf(o0[r] * inv);
            op[32 + c] = f2bf(o1[r] * inv);
        }
    }
}

// ===========================================================================
// FALLBACK PATH (ws too small; not expected). r7 fp32-reg-staged GEMM +
// r9 LDS-staged attention, K|Vt(stride 1500) in d_out.
// ===========================================================================
template <bool ABF>
__device__ __forceinline__ void gemm128(
    const float* __restrict__ Af, const unsigned short* __restrict__ Ab,
    size_t arow0, int avalid,
    const float* __restrict__ W, int wrow0,
    unsigned short* As, unsigned short* Bs,
    int tid, f32x4 acc[4][4])
{
    const int lane = tid & 63;
    const int wm = (tid >> 7), wn = (tid >> 6) & 1;
    float4 pA[8]; short8v pAb[4]; float4 pB[8];

    auto loadT = [&](int k0) {
#pragma unroll
        for (int uu = 0; uu < 4; ++uu) {
            int u = tid + uu * 256, row = u >> 3, sl = (u & 7) * 8;
            if constexpr (ABF) {
                short8v t;
#pragma unroll
                for (int i = 0; i < 8; ++i) t[i] = 0;
                if (row < avalid)
                    t = *(const short8v*)(Ab + (arow0 + row) * E + k0 + sl);
                pAb[uu] = t;
            } else {
                float4 x0 = make_float4(0.f, 0.f, 0.f, 0.f), x1 = x0;
                if (row < avalid) {
                    const float* p = Af + (arow0 + row) * (size_t)E + k0 + sl;
                    x0 = *(const float4*)p; x1 = *(const float4*)(p + 4);
                }
                pA[2 * uu] = x0; pA[2 * uu + 1] = x1;
            }
            const float* q = W + (size_t)(wrow0 + row) * E + k0 + sl;
            pB[2 * uu] = *(const float4*)q;
            pB[2 * uu + 1] = *(const float4*)(q + 4);
        }
    };
    auto commitT = [&]() {
#pragma unroll
        for (int uu = 0; uu < 4; ++uu) {
            int u = tid + uu * 256, row = u >> 3, sl = (u & 7) * 8;
            if constexpr (ABF) {
                *(short8v*)(As + swz(row, sl)) = pAb[uu];
            } else {
                float t[8];
                *(float4*)t = pA[2 * uu]; *(float4*)(t + 4) = pA[2 * uu + 1];
                *(short8v*)(As + swz(row, sl)) = pack8(t);
            }
            float t2[8];
            *(float4*)t2 = pB[2 * uu]; *(float4*)(t2 + 4) = pB[2 * uu + 1];
            *(short8v*)(Bs + swz(row, sl)) = pack8(t2);
        }
    };

    loadT(0);
    for (int k0 = 0; k0 < E; k0 += 64) {
        __syncthreads();
        commitT();
        __syncthreads();
        if (k0 + 64 < E) loadT(k0 + 64);
#pragma unroll
        for (int kk = 0; kk < 64; kk += 32) {
            short8v afr[4], bfr[4];
#pragma unroll
            for (int m = 0; m < 4; ++m)
                afr[m] = *(const short8v*)(As + swz(wm * 64 + m * 16 + (lane & 15),
                                                    kk + (lane >> 4) * 8));
#pragma unroll
            for (int n = 0; n < 4; ++n)
                bfr[n] = *(const short8v*)(Bs + swz(wn * 64 + n * 16 + (lane & 15),
                                                    kk + (lane >> 4) * 8));
            __builtin_amdgcn_s_setprio(1);
#pragma unroll
            for (int m = 0; m < 4; ++m)
#pragma unroll
                for (int n = 0; n < 4; ++n)
                    acc[m][n] = __builtin_amdgcn_mfma_f32_16x16x32_bf16(
                        afr[m], bfr[n], acc[m][n], 0, 0, 0);
            __builtin_amdgcn_s_setprio(0);
        }
    }
}

__global__ __launch_bounds__(256, 2) void proj_kernel(
    const float* __restrict__ X, const float* __restrict__ Wk,
    const float* __restrict__ Wv, const float* __restrict__ bv,
    const float* __restrict__ Wq, const float* __restrict__ bq,
    unsigned short* __restrict__ Kb, unsigned short* __restrict__ Vt,
    unsigned short* __restrict__ Qo)
{
    __shared__ unsigned short As[128 * 64], Bs[128 * 64];
    const int sid = blockIdx.x, cpx = gridDim.x >> 3;
    const int nid = (sid & 7) * cpx + (sid >> 3);
    const int mb = nid / 24, nb = nid % 24;
    const int z = nb >> 3, nbz = nb & 7;
    const size_t m0 = (size_t)mb * 128;
    const int avalid = (M_ - (int)m0) < 128 ? (M_ - (int)m0) : 128;
    const float* W = (z == 0) ? Wk : (z == 1) ? Wv : Wq;

    f32x4 acc[4][4];
#pragma unroll
    for (int m = 0; m < 4; ++m)
#pragma unroll
        for (int n = 0; n < 4; ++n)
#pragma unroll
            for (int i = 0; i < 4; ++i) acc[m][n][i] = 0.f;

    gemm128<false>(X, nullptr, m0, avalid, W, nbz * 128, As, Bs, threadIdx.x, acc);

    const int tid = threadIdx.x, lane = tid & 63;
    const int wm = (tid >> 7), wn = (tid >> 6) & 1;
#pragma unroll
    for (int m = 0; m < 4; ++m) {
        long gi0 = (long)m0 + wm * 64 + m * 16 + (lane >> 4) * 4;
#pragma unroll
        for (int n = 0; n < 4; ++n) {
            int col = nbz * 128 + wn * 64 + n * 16 + (lane & 15);
            if (z == 0) {
#pragma unroll
                for (int rg = 0; rg < 4; ++rg) {
                    long gi = gi0 + rg;
                    if (gi < M_) Kb[(size_t)gi * E + col] = f2bf(acc[m][n][rg]);
                }
            } else if (z == 2) {
                float bias = bq[col];
#pragma unroll
                for (int rg = 0; rg < 4; ++rg) {
                    long gi = gi0 + rg;
                    if (gi < M_)
                        Qo[(size_t)gi * E + col] = f2bf((acc[m][n][rg] + bias) * QSC);
                }
            } else {
                float bias = bv[col];
                if (gi0 + 3 < M_) {
                    long bb = gi0 / SEQ_, t0 = gi0 % SEQ_;
                    union { unsigned int u[2]; ushort4v v; } pk;
                    pk.u[0] = cvt_pk_bf16(acc[m][n][0] + bias, acc[m][n][1] + bias);
                    pk.u[1] = cvt_pk_bf16(acc[m][n][2] + bias, acc[m][n][3] + bias);
                    *(ushort4v*)(Vt + ((size_t)bb * E + col) * SEQ_ + t0) = pk.v;
                } else {
#pragma unroll
                    for (int rg = 0; rg < 4; ++rg) {
                        long gi = gi0 + rg;
                        if (gi < M_) {
                            long bb = gi / SEQ_, t = gi % SEQ_;
                            Vt[((size_t)bb * E + col) * SEQ_ + t] =
                                f2bf(acc[m][n][rg] + bias);
                        }
                    }
                }
            }
        }
    }
}

__global__ __launch_bounds__(256, 2) void oproj_kernel(
    const unsigned short* __restrict__ Ab, const float* __restrict__ Wo,
    const float* __restrict__ bo, float* __restrict__ out)
{
    __shared__ unsigned short As[128 * 64], Bs[128 * 64];
    const int sid = blockIdx.x, cpx = gridDim.x >> 3;
    const int nid = (sid & 7) * cpx + (sid >> 3);
    const int mb = nid >> 3, nb = nid & 7;
    const size_t m0 = (size_t)mb * 128;
    const int avalid = (M_ - (int)m0) < 128 ? (M_ - (int)m0) : 128;

    f32x4 acc[4][4];
#pragma unroll
    for (int m = 0; m < 4; ++m)
#pragma unroll
        for (int n = 0; n < 4; ++n)
#pragma unroll
            for (int i = 0; i < 4; ++i) acc[m][n][i] = 0.f;

    gemm128<true>(nullptr, Ab, m0, avalid, Wo, nb * 128, As, Bs, threadIdx.x, acc);

    const int tid = threadIdx.x, lane = tid & 63;
    const int wm = (tid >> 7), wn = (tid >> 6) & 1;
#pragma unroll
    for (int m = 0; m < 4; ++m) {
        long gi0 = (long)m0 + wm * 64 + m * 16 + (lane >> 4) * 4;
#pragma unroll
        for (int n = 0; n < 4; ++n) {
            int col = nb * 128 + wn * 64 + n * 16 + (lane & 15);
            float bias = bo[col];
#pragma unroll
            for (int rg = 0; rg < 4; ++rg) {
                long gi = gi0 + rg;
                if (gi < M_) out[(size_t)gi * E + col] = acc[m][n][rg] + bias;
            }
        }
    }
}

__global__ __launch_bounds__(256, 4) void attn_fallback(
    const unsigned short* __restrict__ Kb,
    const unsigned short* __restrict__ Vt,
    unsigned short* __restrict__ Qa)
{
    __shared__ unsigned short ks[2][32 * 128], vs[2][32 * 128];
    const int sid = blockIdx.x;
    const int nid = (sid & 7) * 96 + (sid >> 3);
    const int bh = nid / 12, qb = nid % 12;
    const int b = bh >> 4, hh = bh & 15;
    const int tid = threadIdx.x, lane = tid & 63, wz = tid >> 6;
    const int c = lane & 31, g2 = lane >> 5;
    const int q0 = qb * 128 + wz * 32;

    const unsigned short* kbase = Kb + (size_t)b * SEQ_ * E + hh * 64;
    const unsigned short* vbase = Vt + ((size_t)b * E + hh * 64) * SEQ_;

    short8v kreg[2];
    ushort4v vreg[4];
    auto loadK = [&](int kt0) {
#pragma unroll
        for (int uu = 0; uu < 2; ++uu) {
            int u = tid + uu * 256, key = u >> 3, slot = (u & 7) * 8;
            short8v t;
#pragma unroll
            for (int i = 0; i < 8; ++i) t[i] = 0;
            int gk = kt0 + key;
            if (gk < SEQ_) t = *(const short8v*)(kbase + (size_t)gk * E + slot);
            kreg[uu] = t;
        }
    };
    auto loadV = [&](int kt0) {
#pragma unroll
        for (int uu = 0; uu < 4; ++uu) {
            int u = tid + uu * 256, d = u >> 4, q4 = (u & 15) * 4;
            ushort4v t; t[0] = t[1] = t[2] = t[3] = 0;
            int col = kt0 + q4, rem = SEQ_ - col;
            const unsigned short* src = vbase + (size_t)d * SEQ_ + col;
            if (rem >= 4) t = *(const ushort4v*)src;
            else if (rem > 0) { for (int e2 = 0; e2 < 4; ++e2) if (e2 < rem) t[e2] = src[e2]; }
            vreg[uu] = t;
        }
    };
    auto commitKV = [&](unsigned short* kd, unsigned short* vd) {
#pragma unroll
        for (int uu = 0; uu < 2; ++uu) {
            int u = tid + uu * 256;
            *(short8v*)(kd + swzf(u >> 3, (u & 7) * 8)) = kreg[uu];
        }
#pragma unroll
        for (int uu = 0; uu < 4; ++uu) {
            int u = tid + uu * 256;
            *(ushort4v*)(vd + swzf(u >> 4, (u & 15) * 4)) = vreg[uu];
        }
    };

    loadK(0); loadV(0);

    short8v qf[4];
    {
        int qr = q0 + c;
        bool ok = qr < SEQ_;
        const unsigned short* qp = Qa + ((size_t)b * SEQ_ + qr) * E + hh * 64 + 8 * g2;
#pragma unroll
        for (int t = 0; t < 4; ++t) {
            short8v zv;
#pragma unroll
            for (int i = 0; i < 8; ++i) zv[i] = 0;
            if (ok) zv = *(const short8v*)(qp + t * 16);
            qf[t] = zv;
        }
    }

    f32x16 o0, o1;
#pragma unroll
    for (int i = 0; i < 16; ++i) { o0[i] = 0.f; o1[i] = 0.f; }
    float lsum = 0.f;

    commitKV(ks[0], vs[0]);
    __syncthreads();
    loadK(64); loadV(64);

    const int NT = (SEQ_ + 63) / 64;     // 24
    for (int it = 0; it < NT; ++it) {
        const int kt0 = it * 64;
        const unsigned short* kcur = ks[it & 1];
        const unsigned short* vcur = vs[it & 1];
        const bool tail = (kt0 + 64 > SEQ_);

#pragma unroll
        for (int nt = 0; nt < 2; ++nt) {
            f32x16 s;
#pragma unroll
            for (int i = 0; i < 16; ++i) s[i] = 0.f;
#pragma unroll
            for (int t = 0; t < 4; ++t) {
                short8v af = *(const short8v*)(kcur + swzf(nt * 32 + c, t * 16 + 8 * g2));
                s = __builtin_amdgcn_mfma_f32_32x32x16_bf16(af, qf[t], s, 0, 0, 0);
            }
            if (tail) {
#pragma unroll
                for (int r = 0; r < 16; ++r) {
                    int key = kt0 + nt * 32 + (r & 3) + 8 * (r >> 2) + 4 * g2;
                    if (key >= SEQ_) s[r] = -1e30f;
                }
            }
            unsigned int pk[8];
            float ls0 = 0.f, ls1 = 0.f;
#pragma unroll
            for (int h = 0; h < 8; ++h) {
                float p0 = __builtin_amdgcn_exp2f(s[2 * h]);
                float p1 = __builtin_amdgcn_exp2f(s[2 * h + 1]);
                if (h & 1) ls1 += p0 + p1; else ls0 += p0 + p1;
                pk[h] = cvt_pk_bf16(p0, p1);
            }
            lsum += ls0 + ls1;
            perml32(pk[0], pk[2]); perml32(pk[1], pk[3]);
            perml32(pk[4], pk[6]); perml32(pk[5], pk[7]);
#pragma unroll
            for (int tau = 0; tau < 2; ++tau) {
                union { unsigned int ww[4]; short8v v; } pa;
                pa.ww[0] = pk[4 * tau + 0];
                pa.ww[1] = pk[4 * tau + 1];
                pa.ww[2] = pk[4 * tau + 2];
                pa.ww[3] = pk[4 * tau + 3];
                int t = nt * 2 + tau;
                short8v vb0 = *(const short8v*)(vcur + swzf(0 + c, t * 16 + 8 * g2));
                short8v vb1 = *(const short8v*)(vcur + swzf(32 + c, t * 16 + 8 * g2));
                o0 = __builtin_amdgcn_mfma_f32_32x32x16_bf16(pa.v, vb0, o0, 0, 0, 0);
                o1 = __builtin_amdgcn_mfma_f32_32x32x16_bf16(pa.v, vb1, o1, 0, 0, 0);
            }
        }

        if (it + 1 < NT) {
            commitKV(ks[(it + 1) & 1], vs[(it + 1) & 1]);
            __syncthreads();
            if (it + 2 < NT) { loadK(kt0 + 128); loadV(kt0 + 128); }
        }
    }

    lsum += __shfl_xor(lsum, 32, 64);
    __syncthreads();
    float* lf = (float*)ks[0] + wz * 32;
    if (lane < 32) lf[c] = 1.0f / lsum;
#pragma unroll
    for (int r = 0; r < 16; ++r) {
        int ql = (r & 3) + 8 * (r >> 2) + 4 * g2;
        int tq = q0 + ql;
        if (tq < SEQ_) {
            float inv = lf[ql];
            unsigned short* op = Qa + ((size_t)b * SEQ_ + tq) * E + hh * 64;
            op[c] = f2bf(o0[r] * inv);
            op[32 + c] = f2bf(o1[r] * inv);
        }
    }
}

extern "C" void kernel_launch(void* const* d_in, const int* in_sizes, int n_in,
                              void* d_out, int out_size, void* d_ws, size_t ws_size,
                              hipStream_t stream) {
    const float* hs = (const float*)d_in[0];
    const float* Wq = (const float*)d_in[1];
    const float* bq = (const float*)d_in[2];
    const float* Wk = (const float*)d_in[3];
    const float* Wv = (const float*)d_in[4];
    const float* bv = (const float*)d_in[5];
    const float* Wo = (const float*)d_in[6];
    const float* bo = (const float*)d_in[7];

    unsigned short* Kb = (unsigned short*)d_out;     // K bf16, overwritten by oproj
    unsigned short* ws = (unsigned short*)d_ws;
    unsigned short* Qa = ws + QA_OFF;
    float* out = (float*)d_out;

    if (ws_size >= WS_FAST_BYTES) {
        unsigned short* Vt = ws + VT_OFF;            // padded V^T in ws
        cvt_kernel<<<dim3(5057), 256, 0, stream>>>(hs, Wk, Wv, Wq, Wo, ws);
        proj_fast<<<dim3(1128), 256, 0, stream>>>(ws + XB_OFF, ws + WB_OFF,
                                                  bv, bq, Kb, Vt, Qa);
        attn_gl<<<dim3(768), 256, 0, stream>>>(Kb, Vt, Qa);
        oproj_fast<<<dim3(376), 256, 0, stream>>>(Qa, ws + WOB_OFF, bo, out);
    } else {
        // fallback: r7 proj + r9 attn, K|Vt(stride 1500) in d_out
        unsigned short* Vt = (unsigned short*)d_out + SZE;
        proj_kernel<<<dim3(47 * 24), 256, 0, stream>>>(hs, Wk, Wv, bv, Wq, bq,
                                                       Kb, Vt, Qa);
        attn_fallback<<<dim3(768), 256, 0, stream>>>(Kb, Vt, Qa);
        oproj_kernel<<<dim3(47 * 8), 256, 0, stream>>>(Qa, Wo, bo, out);
    }
}